// Round 3
// baseline (3580.738 us; speedup 1.0000x reference)
//
#include <hip/hip_runtime.h>
#include <hip/hip_bf16.h>

#define NN 100000      // nodes
#define NE 200000      // edges
#define NF 56          // atom feats
#define HD 256         // hidden
#define NG 2048        // graphs

// ---- param prep -------------------------------------------------------------
// base[c] = sum_f emb[f][0][c];  delta[f][c] = emb[f][1][c] - emb[f][0][c]
__global__ void prep_emb(const float* __restrict__ emb,
                         float* __restrict__ base, float* __restrict__ delta) {
    int c = threadIdx.x;
    int f = blockIdx.x;
    if (f < NF) {
        float e0 = emb[(f * 2 + 0) * HD + c];
        float e1 = emb[(f * 2 + 1) * HD + c];
        delta[f * HD + c] = e1 - e0;
    } else {
        float s = 0.f;
        for (int ff = 0; ff < NF; ++ff) s += emb[(ff * 2) * HD + c];
        base[c] = s;
    }
}

// ---- degree / norm ----------------------------------------------------------
__global__ void deg_kernel(const int* __restrict__ dst, unsigned* __restrict__ deg, int E) {
    int e = blockIdx.x * blockDim.x + threadIdx.x;
    if (e < E) atomicAdd(&deg[dst[e]], 1u);
}

__global__ void dinv_kernel(const unsigned* __restrict__ deg, float* __restrict__ dinv,
                            float* __restrict__ selfn) {
    int v = blockIdx.x * blockDim.x + threadIdx.x;
    if (v < NN) {
        float d = (float)(deg[v] + 1u);   // +1 self loop
        dinv[v]  = rsqrtf(d);
        selfn[v] = 1.0f / d;              // dinv^2
    }
}

__global__ void norm_kernel(const int* __restrict__ src, const int* __restrict__ dst,
                            const float* __restrict__ dinv, float* __restrict__ norm, int E) {
    int e = blockIdx.x * blockDim.x + threadIdx.x;
    if (e < E) norm[e] = dinv[src[e]] * dinv[dst[e]];
}

// ---- atom encoder: h[n][c] = base[c] + sum_f x[n][f] ? delta[f][c] ----------
__global__ void __launch_bounds__(256) atom_encoder(const int* __restrict__ x,
                                                    const float* __restrict__ base,
                                                    const float* __restrict__ delta,
                                                    float* __restrict__ h) {
    __shared__ float sdelta[NF * HD];   // 57344 B
    __shared__ float sbase[HD];
    __shared__ int xrow[NF];
    int t = threadIdx.x;
    for (int i = t; i < NF * HD; i += 256) sdelta[i] = delta[i];
    sbase[t] = base[t];
    __syncthreads();
    for (int n = blockIdx.x; n < NN; n += gridDim.x) {
        if (t < NF) xrow[t] = x[n * NF + t];
        __syncthreads();
        float acc = sbase[t];
#pragma unroll
        for (int f = 0; f < NF; ++f)
            acc += xrow[f] ? sdelta[f * HD + t] : 0.0f;
        h[n * HD + t] = acc;
        __syncthreads();
    }
}

// ---- f32 GEMM: C[M,256] = A[M,256] @ B[256,256], 128x128 tile, 8x8/thread ---
__global__ void __launch_bounds__(256) gemm_f32(const float* __restrict__ A,
                                                const float* __restrict__ B,
                                                float* __restrict__ C, int M) {
    __shared__ float sA[8][128];
    __shared__ float sB[8][128];
    int t = threadIdx.x;
    int m0 = blockIdx.x * 128;
    int n0 = blockIdx.y * 128;
    int arow = t >> 1, ak = (t & 1) * 4;
    int brow = t >> 5, bcol = (t & 31) * 4;
    int tm = (t & 15) * 8, tn = (t >> 4) * 8;
    float acc[8][8] = {};
    for (int k0 = 0; k0 < 256; k0 += 8) {
        float4 av = make_float4(0.f, 0.f, 0.f, 0.f);
        if (m0 + arow < M) av = *(const float4*)&A[(size_t)(m0 + arow) * HD + k0 + ak];
        float4 bv = *(const float4*)&B[(size_t)(k0 + brow) * HD + n0 + bcol];
        __syncthreads();
        sA[ak + 0][arow] = av.x; sA[ak + 1][arow] = av.y;
        sA[ak + 2][arow] = av.z; sA[ak + 3][arow] = av.w;
        *(float4*)&sB[brow][bcol] = bv;
        __syncthreads();
#pragma unroll
        for (int kk = 0; kk < 8; ++kk) {
            float4 a0 = *(const float4*)&sA[kk][tm];
            float4 a1 = *(const float4*)&sA[kk][tm + 4];
            float4 b0 = *(const float4*)&sB[kk][tn];
            float4 b1 = *(const float4*)&sB[kk][tn + 4];
            float a[8] = {a0.x, a0.y, a0.z, a0.w, a1.x, a1.y, a1.z, a1.w};
            float b[8] = {b0.x, b0.y, b0.z, b0.w, b1.x, b1.y, b1.z, b1.w};
#pragma unroll
            for (int i = 0; i < 8; ++i)
#pragma unroll
                for (int j = 0; j < 8; ++j)
                    acc[i][j] += a[i] * b[j];
        }
    }
#pragma unroll
    for (int i = 0; i < 8; ++i) {
        int row = m0 + tm + i;
        if (row < M) {
            *(float4*)&C[(size_t)row * HD + n0 + tn]     = make_float4(acc[i][0], acc[i][1], acc[i][2], acc[i][3]);
            *(float4*)&C[(size_t)row * HD + n0 + tn + 4] = make_float4(acc[i][4], acc[i][5], acc[i][6], acc[i][7]);
        }
    }
}

// ---- conv aggregation -------------------------------------------------------
// agg[v] = hw[v] * selfnorm[v] + bias   (non-atomic init; runs before scatter)
__global__ void selfloop_init(const float* __restrict__ hw, const float* __restrict__ selfn,
                              const float* __restrict__ bias, float* __restrict__ agg) {
    int idx = blockIdx.x * blockDim.x + threadIdx.x;   // over NN*64 float4s
    if (idx < NN * 64) {
        int n = idx >> 6;
        int c4 = (idx & 63) * 4;
        float s = selfn[n];
        float4 v = *(const float4*)&hw[(size_t)n * HD + c4];
        float4 o;
        o.x = v.x * s + bias[c4 + 0];
        o.y = v.y * s + bias[c4 + 1];
        o.z = v.z * s + bias[c4 + 2];
        o.w = v.w * s + bias[c4 + 3];
        *(float4*)&agg[(size_t)n * HD + c4] = o;
    }
}

__global__ void __launch_bounds__(256) edge_scatter(const int* __restrict__ src,
                                                    const int* __restrict__ dst,
                                                    const float* __restrict__ norm,
                                                    const float* __restrict__ hw,
                                                    float* __restrict__ agg, int E) {
    int tid = blockIdx.x * 256 + threadIdx.x;
    int e = tid >> 6;
    if (e >= E) return;
    int c4 = (tid & 63) * 4;
    int s = src[e], d = dst[e];
    float nm = norm[e];
    float4 v = *(const float4*)&hw[(size_t)s * HD + c4];
    float* ap = &agg[(size_t)d * HD + c4];
    unsafeAtomicAdd(ap + 0, v.x * nm);
    unsafeAtomicAdd(ap + 1, v.y * nm);
    unsafeAtomicAdd(ap + 2, v.z * nm);
    unsafeAtomicAdd(ap + 3, v.w * nm);
}

// ---- batchnorm --------------------------------------------------------------
__global__ void bn_stats(const float* __restrict__ h, float* __restrict__ sums) {
    int c = threadIdx.x;
    float s = 0.f, ss = 0.f;
    for (int r = blockIdx.x; r < NN; r += gridDim.x) {
        float v = h[(size_t)r * HD + c];
        s += v; ss += v * v;
    }
    unsafeAtomicAdd(&sums[c], s);
    unsafeAtomicAdd(&sums[HD + c], ss);
}

__global__ void bn_finalize(const float* __restrict__ sums,
                            const float* __restrict__ gamma,
                            const float* __restrict__ beta,
                            float* __restrict__ scale, float* __restrict__ shift) {
    int c = threadIdx.x;
    const float inv_n = 1.0f / (float)NN;
    float mu  = sums[c] * inv_n;
    float var = sums[HD + c] * inv_n - mu * mu;
    float rstd = rsqrtf(var + 1e-5f);
    float sc = gamma[c] * rstd;
    scale[c] = sc;
    shift[c] = beta[c] - mu * sc;
}

__global__ void bn_apply_relu(float* __restrict__ h, const float* __restrict__ scale,
                              const float* __restrict__ shift) {
    int idx = blockIdx.x * blockDim.x + threadIdx.x;   // NN*64 float4s
    if (idx < NN * 64) {
        int c4 = (idx & 63) * 4;
        float4 v = *(float4*)&h[(size_t)idx * 4];
        float4 o;
        o.x = fmaxf(v.x * scale[c4 + 0] + shift[c4 + 0], 0.f);
        o.y = fmaxf(v.y * scale[c4 + 1] + shift[c4 + 1], 0.f);
        o.z = fmaxf(v.z * scale[c4 + 2] + shift[c4 + 2], 0.f);
        o.w = fmaxf(v.w * scale[c4 + 3] + shift[c4 + 3], 0.f);
        *(float4*)&h[(size_t)idx * 4] = o;
    }
}

// ---- pooling + linear -------------------------------------------------------
__global__ void __launch_bounds__(256) pool_dot(const float* __restrict__ h,
                                                const float* __restrict__ lw,
                                                const int* __restrict__ batch,
                                                float* __restrict__ gsum, float* __restrict__ gcnt) {
    int tid = blockIdx.x * 256 + threadIdx.x;
    int n = tid >> 6;
    if (n >= NN) return;
    int l = tid & 63;
    int c4 = l * 4;
    float4 v = *(const float4*)&h[(size_t)n * HD + c4];
    float s = v.x * lw[c4] + v.y * lw[c4 + 1] + v.z * lw[c4 + 2] + v.w * lw[c4 + 3];
#pragma unroll
    for (int off = 32; off > 0; off >>= 1) s += __shfl_down(s, off, 64);
    if (l == 0) {
        int g = batch[n];
        unsafeAtomicAdd(&gsum[g], s);
        unsafeAtomicAdd(&gcnt[g], 1.0f);
    }
}

__global__ void final_out(const float* __restrict__ gsum, const float* __restrict__ gcnt,
                          const float* __restrict__ lb, float* __restrict__ out) {
    int g = blockIdx.x * blockDim.x + threadIdx.x;
    if (g < NG) {
        float p = gsum[g] / fmaxf(gcnt[g], 1.0f);
        out[g] = p + lb[0];
    }
}

// ---- driver -----------------------------------------------------------------
extern "C" void kernel_launch(void* const* d_in, const int* in_sizes, int n_in,
                              void* d_out, int out_size, void* d_ws, size_t ws_size,
                              hipStream_t stream) {
    const int*   x     = (const int*)d_in[0];
    const int*   ei    = (const int*)d_in[1];
    const int*   batch = (const int*)d_in[2];
    const float* emb   = (const float*)d_in[3];
    const float* Ws    = (const float*)d_in[4];
    const float* bs    = (const float*)d_in[5];
    const float* gam   = (const float*)d_in[6];
    const float* bet   = (const float*)d_in[7];
    const float* lw    = (const float*)d_in[8];
    const float* lb    = (const float*)d_in[9];
    float* out = (float*)d_out;

    const int* src = ei;
    const int* dst = ei + NE;

    // workspace carve-up (256-B aligned)
    char* p = (char*)d_ws;
    size_t off = 0;
    auto carve = [&](size_t bytes) { void* r = p + off; off = (off + bytes + 255) & ~(size_t)255; return r; };
    float*    buf0  = (float*)carve((size_t)NN * HD * 4);
    float*    buf1  = (float*)carve((size_t)NN * HD * 4);
    float*    base  = (float*)carve(HD * 4);
    float*    delta = (float*)carve(NF * HD * 4);
    unsigned* deg   = (unsigned*)carve(NN * 4);
    float*    dinv  = (float*)carve(NN * 4);
    float*    selfn = (float*)carve(NN * 4);
    float*    norm  = (float*)carve(NE * 4);
    float*    bnsum = (float*)carve(2 * HD * 4);
    float*    scale = (float*)carve(HD * 4);
    float*    shift = (float*)carve(HD * 4);
    float*    gsum  = (float*)carve(NG * 4);
    float*    gcnt  = (float*)carve(NG * 4);
    (void)ws_size; (void)n_in; (void)in_sizes; (void)out_size;

    // params
    prep_emb<<<NF + 1, HD, 0, stream>>>(emb, base, delta);

    // degrees & norms
    hipMemsetAsync(deg, 0, NN * 4, stream);
    deg_kernel<<<(NE + 255) / 256, 256, 0, stream>>>(dst, deg, NE);
    dinv_kernel<<<(NN + 255) / 256, 256, 0, stream>>>(deg, dinv, selfn);
    norm_kernel<<<(NE + 255) / 256, 256, 0, stream>>>(src, dst, dinv, norm, NE);

    // encoder -> buf0
    atom_encoder<<<2048, 256, 0, stream>>>(x, base, delta, buf0);

    // 3 GCN layers, h ping-pongs buf0 -> buf1(hw) -> buf0(agg)
    for (int i = 0; i < 3; ++i) {
        gemm_f32<<<dim3((NN + 127) / 128, 2), 256, 0, stream>>>(buf0, Ws + (size_t)i * HD * HD, buf1, NN);
        selfloop_init<<<(NN * 64 + 255) / 256, 256, 0, stream>>>(buf1, selfn, bs + i * HD, buf0);
        edge_scatter<<<(NE * 64) / 256, 256, 0, stream>>>(src, dst, norm, buf1, buf0, NE);
        if (i < 2) {
            hipMemsetAsync(bnsum, 0, 2 * HD * 4, stream);
            bn_stats<<<512, 256, 0, stream>>>(buf0, bnsum);
            bn_finalize<<<1, HD, 0, stream>>>(bnsum, gam + i * HD, bet + i * HD, scale, shift);
            bn_apply_relu<<<(NN * 64 + 255) / 256, 256, 0, stream>>>(buf0, scale, shift);
        }
    }

    // pool + linear
    hipMemsetAsync(gsum, 0, NG * 4, stream);
    hipMemsetAsync(gcnt, 0, NG * 4, stream);
    pool_dot<<<(NN * 64 + 255) / 256, 256, 0, stream>>>(buf0, lw, batch, gsum, gcnt);
    final_out<<<(NG + 255) / 256, 256, 0, stream>>>(gsum, gcnt, lb, out);
}

// Round 4
// 1658.232 us; speedup vs baseline: 2.1594x; 2.1594x over previous
//
#include <hip/hip_runtime.h>
#include <hip/hip_bf16.h>

#define NN 100000      // nodes
#define NE 200000      // edges
#define NF 56          // atom feats
#define HD 256         // hidden
#define NG 2048        // graphs

#define SCAN_CH 512
#define NCH ((NN + SCAN_CH - 1) / SCAN_CH)   // 196 chunks

// ---- param prep -------------------------------------------------------------
__global__ void prep_emb(const float* __restrict__ emb,
                         float* __restrict__ base, float* __restrict__ delta) {
    int c = threadIdx.x;
    int f = blockIdx.x;
    if (f < NF) {
        float e0 = emb[(f * 2 + 0) * HD + c];
        float e1 = emb[(f * 2 + 1) * HD + c];
        delta[f * HD + c] = e1 - e0;
    } else {
        float s = 0.f;
        for (int ff = 0; ff < NF; ++ff) s += emb[(ff * 2) * HD + c];
        base[c] = s;
    }
}

// ---- degree / norm ----------------------------------------------------------
__global__ void deg_kernel(const int* __restrict__ dst, unsigned* __restrict__ deg, int E) {
    int e = blockIdx.x * blockDim.x + threadIdx.x;
    if (e < E) atomicAdd(&deg[dst[e]], 1u);
}

__global__ void dinv_kernel(const unsigned* __restrict__ deg, float* __restrict__ dinv,
                            float* __restrict__ selfn) {
    int v = blockIdx.x * blockDim.x + threadIdx.x;
    if (v < NN) {
        float d = (float)(deg[v] + 1u);   // +1 self loop
        dinv[v]  = rsqrtf(d);
        selfn[v] = 1.0f / d;              // dinv^2
    }
}

__global__ void norm_kernel(const int* __restrict__ src, const int* __restrict__ dst,
                            const float* __restrict__ dinv, float* __restrict__ norm, int E) {
    int e = blockIdx.x * blockDim.x + threadIdx.x;
    if (e < E) norm[e] = dinv[src[e]] * dinv[dst[e]];
}

// ---- CSR build: hierarchical exclusive scan of deg + counting-sort fill -----
__global__ void chunk_sum(const unsigned* __restrict__ deg, unsigned* __restrict__ csum) {
    __shared__ unsigned s[SCAN_CH];
    int t = threadIdx.x;
    int base = blockIdx.x * SCAN_CH;
    s[t] = (base + t < NN) ? deg[base + t] : 0u;
    __syncthreads();
    for (int off = SCAN_CH / 2; off > 0; off >>= 1) {
        if (t < off) s[t] += s[t + off];
        __syncthreads();
    }
    if (t == 0) csum[blockIdx.x] = s[0];
}

__global__ void chunk_scan(unsigned* __restrict__ csum, int n) {  // 1 block, 256 thr
    __shared__ unsigned s[256];
    int t = threadIdx.x;
    unsigned v = (t < n) ? csum[t] : 0u;
    s[t] = v;
    __syncthreads();
    for (int off = 1; off < 256; off <<= 1) {
        unsigned add = (t >= off) ? s[t - off] : 0u;
        __syncthreads();
        s[t] += add;
        __syncthreads();
    }
    if (t < n) csum[t] = s[t] - v;   // exclusive
}

__global__ void chunk_apply(const unsigned* __restrict__ deg, const unsigned* __restrict__ csum,
                            unsigned* __restrict__ row_start, unsigned* __restrict__ cursor) {
    __shared__ unsigned s[SCAN_CH];
    int t = threadIdx.x;
    int base = blockIdx.x * SCAN_CH;
    unsigned v = (base + t < NN) ? deg[base + t] : 0u;
    s[t] = v;
    __syncthreads();
    for (int off = 1; off < SCAN_CH; off <<= 1) {
        unsigned add = (t >= off) ? s[t - off] : 0u;
        __syncthreads();
        s[t] += add;
        __syncthreads();
    }
    if (base + t < NN) {
        unsigned rs = csum[blockIdx.x] + s[t] - v;   // exclusive scan value
        row_start[base + t] = rs;
        cursor[base + t] = rs;
    }
    if (blockIdx.x == 0 && t == 0) row_start[NN] = NE;
}

__global__ void csr_fill(const int* __restrict__ src, const int* __restrict__ dst,
                         const float* __restrict__ norm, unsigned* __restrict__ cursor,
                         int* __restrict__ ecol, float* __restrict__ enorm, int E) {
    int e = blockIdx.x * blockDim.x + threadIdx.x;
    if (e < E) {
        unsigned pos = atomicAdd(&cursor[dst[e]], 1u);
        ecol[pos] = src[e];
        enorm[pos] = norm[e];
    }
}

// ---- atom encoder: h[n][c] = base[c] + sum_f x[n][f] ? delta[f][c] ----------
__global__ void __launch_bounds__(256) atom_encoder(const int* __restrict__ x,
                                                    const float* __restrict__ base,
                                                    const float* __restrict__ delta,
                                                    float* __restrict__ h) {
    __shared__ float sdelta[NF * HD];   // 57344 B
    __shared__ float sbase[HD];
    __shared__ int xrow[NF];
    int t = threadIdx.x;
    for (int i = t; i < NF * HD; i += 256) sdelta[i] = delta[i];
    sbase[t] = base[t];
    __syncthreads();
    for (int n = blockIdx.x; n < NN; n += gridDim.x) {
        if (t < NF) xrow[t] = x[n * NF + t];
        __syncthreads();
        float acc = sbase[t];
#pragma unroll
        for (int f = 0; f < NF; ++f)
            acc += xrow[f] ? sdelta[f * HD + t] : 0.0f;
        h[n * HD + t] = acc;
        __syncthreads();
    }
}

// ---- f32 GEMM: C = relu_bn(A) @ B, 128x128 tile, 8x8/thread -----------------
// ascale/ashift == nullptr -> identity (no BN) on A load.
__global__ void __launch_bounds__(256) gemm_f32(const float* __restrict__ A,
                                                const float* __restrict__ B,
                                                float* __restrict__ C, int M,
                                                const float* __restrict__ ascale,
                                                const float* __restrict__ ashift) {
    __shared__ float sA[8][128];
    __shared__ float sB[8][128];
    int t = threadIdx.x;
    int m0 = blockIdx.x * 128;
    int n0 = blockIdx.y * 128;
    int arow = t >> 1, ak = (t & 1) * 4;
    int brow = t >> 5, bcol = (t & 31) * 4;
    int tm = (t & 15) * 8, tn = (t >> 4) * 8;
    float acc[8][8] = {};
    for (int k0 = 0; k0 < 256; k0 += 8) {
        float4 av = make_float4(0.f, 0.f, 0.f, 0.f);
        if (m0 + arow < M) {
            av = *(const float4*)&A[(size_t)(m0 + arow) * HD + k0 + ak];
            if (ascale) {   // fused batchnorm-apply + relu on the A operand
                av.x = fmaxf(av.x * ascale[k0 + ak + 0] + ashift[k0 + ak + 0], 0.f);
                av.y = fmaxf(av.y * ascale[k0 + ak + 1] + ashift[k0 + ak + 1], 0.f);
                av.z = fmaxf(av.z * ascale[k0 + ak + 2] + ashift[k0 + ak + 2], 0.f);
                av.w = fmaxf(av.w * ascale[k0 + ak + 3] + ashift[k0 + ak + 3], 0.f);
            }
        }
        float4 bv = *(const float4*)&B[(size_t)(k0 + brow) * HD + n0 + bcol];
        __syncthreads();
        sA[ak + 0][arow] = av.x; sA[ak + 1][arow] = av.y;
        sA[ak + 2][arow] = av.z; sA[ak + 3][arow] = av.w;
        *(float4*)&sB[brow][bcol] = bv;
        __syncthreads();
#pragma unroll
        for (int kk = 0; kk < 8; ++kk) {
            float4 a0 = *(const float4*)&sA[kk][tm];
            float4 a1 = *(const float4*)&sA[kk][tm + 4];
            float4 b0 = *(const float4*)&sB[kk][tn];
            float4 b1 = *(const float4*)&sB[kk][tn + 4];
            float a[8] = {a0.x, a0.y, a0.z, a0.w, a1.x, a1.y, a1.z, a1.w};
            float b[8] = {b0.x, b0.y, b0.z, b0.w, b1.x, b1.y, b1.z, b1.w};
#pragma unroll
            for (int i = 0; i < 8; ++i)
#pragma unroll
                for (int j = 0; j < 8; ++j)
                    acc[i][j] += a[i] * b[j];
        }
    }
#pragma unroll
    for (int i = 0; i < 8; ++i) {
        int row = m0 + tm + i;
        if (row < M) {
            *(float4*)&C[(size_t)row * HD + n0 + tn]     = make_float4(acc[i][0], acc[i][1], acc[i][2], acc[i][3]);
            *(float4*)&C[(size_t)row * HD + n0 + tn + 4] = make_float4(acc[i][4], acc[i][5], acc[i][6], acc[i][7]);
        }
    }
}

// ---- CSR gather-aggregate: one 64-lane wave per dst node --------------------
// agg[n] = hw[n]*selfn[n] + bias + sum_{e in CSR[n]} enorm[e] * hw[ecol[e]]
__global__ void __launch_bounds__(256) gcn_aggregate(const float* __restrict__ hw,
                                                     const float* __restrict__ selfn,
                                                     const float* __restrict__ bias,
                                                     const unsigned* __restrict__ row_start,
                                                     const int* __restrict__ ecol,
                                                     const float* __restrict__ enorm,
                                                     float* __restrict__ agg) {
    int tid = blockIdx.x * 256 + threadIdx.x;
    int n = tid >> 6;            // one wave (64 lanes) per node -> uniform edge loop
    if (n >= NN) return;
    int c4 = (tid & 63) * 4;
    float s = selfn[n];
    float4 v = *(const float4*)&hw[(size_t)n * HD + c4];
    float4 acc;
    acc.x = v.x * s + bias[c4 + 0];
    acc.y = v.y * s + bias[c4 + 1];
    acc.z = v.z * s + bias[c4 + 2];
    acc.w = v.w * s + bias[c4 + 3];
    unsigned e0 = row_start[n], e1 = row_start[n + 1];
    for (unsigned e = e0; e < e1; ++e) {
        int sv = ecol[e];
        float nm = enorm[e];
        float4 u = *(const float4*)&hw[(size_t)sv * HD + c4];
        acc.x += u.x * nm;
        acc.y += u.y * nm;
        acc.z += u.z * nm;
        acc.w += u.w * nm;
    }
    *(float4*)&agg[(size_t)n * HD + c4] = acc;
}

// ---- batchnorm stats --------------------------------------------------------
__global__ void bn_stats(const float* __restrict__ h, float* __restrict__ sums) {
    int c = threadIdx.x;
    float s = 0.f, ss = 0.f;
    for (int r = blockIdx.x; r < NN; r += gridDim.x) {
        float v = h[(size_t)r * HD + c];
        s += v; ss += v * v;
    }
    unsafeAtomicAdd(&sums[c], s);
    unsafeAtomicAdd(&sums[HD + c], ss);
}

__global__ void bn_finalize(const float* __restrict__ sums,
                            const float* __restrict__ gamma,
                            const float* __restrict__ beta,
                            float* __restrict__ scale, float* __restrict__ shift) {
    int c = threadIdx.x;
    const float inv_n = 1.0f / (float)NN;
    float mu  = sums[c] * inv_n;
    float var = sums[HD + c] * inv_n - mu * mu;
    float rstd = rsqrtf(var + 1e-5f);
    float sc = gamma[c] * rstd;
    scale[c] = sc;
    shift[c] = beta[c] - mu * sc;
}

// ---- pooling + linear -------------------------------------------------------
__global__ void __launch_bounds__(256) pool_dot(const float* __restrict__ h,
                                                const float* __restrict__ lw,
                                                const int* __restrict__ batch,
                                                float* __restrict__ gsum, float* __restrict__ gcnt) {
    int tid = blockIdx.x * 256 + threadIdx.x;
    int n = tid >> 6;
    if (n >= NN) return;
    int l = tid & 63;
    int c4 = l * 4;
    float4 v = *(const float4*)&h[(size_t)n * HD + c4];
    float s = v.x * lw[c4] + v.y * lw[c4 + 1] + v.z * lw[c4 + 2] + v.w * lw[c4 + 3];
#pragma unroll
    for (int off = 32; off > 0; off >>= 1) s += __shfl_down(s, off, 64);
    if (l == 0) {
        int g = batch[n];
        unsafeAtomicAdd(&gsum[g], s);
        unsafeAtomicAdd(&gcnt[g], 1.0f);
    }
}

__global__ void final_out(const float* __restrict__ gsum, const float* __restrict__ gcnt,
                          const float* __restrict__ lb, float* __restrict__ out) {
    int g = blockIdx.x * blockDim.x + threadIdx.x;
    if (g < NG) {
        float p = gsum[g] / fmaxf(gcnt[g], 1.0f);
        out[g] = p + lb[0];
    }
}

// ---- driver -----------------------------------------------------------------
extern "C" void kernel_launch(void* const* d_in, const int* in_sizes, int n_in,
                              void* d_out, int out_size, void* d_ws, size_t ws_size,
                              hipStream_t stream) {
    const int*   x     = (const int*)d_in[0];
    const int*   ei    = (const int*)d_in[1];
    const int*   batch = (const int*)d_in[2];
    const float* emb   = (const float*)d_in[3];
    const float* Ws    = (const float*)d_in[4];
    const float* bs    = (const float*)d_in[5];
    const float* gam   = (const float*)d_in[6];
    const float* bet   = (const float*)d_in[7];
    const float* lw    = (const float*)d_in[8];
    const float* lb    = (const float*)d_in[9];
    float* out = (float*)d_out;

    const int* src = ei;
    const int* dst = ei + NE;

    // workspace carve-up (256-B aligned)
    char* p = (char*)d_ws;
    size_t off = 0;
    auto carve = [&](size_t bytes) { void* r = p + off; off = (off + bytes + 255) & ~(size_t)255; return r; };
    float*    buf0   = (float*)carve((size_t)NN * HD * 4);
    float*    buf1   = (float*)carve((size_t)NN * HD * 4);
    float*    base   = (float*)carve(HD * 4);
    float*    delta  = (float*)carve(NF * HD * 4);
    unsigned* deg    = (unsigned*)carve(NN * 4);
    float*    dinv   = (float*)carve(NN * 4);
    float*    selfn  = (float*)carve(NN * 4);
    float*    norm   = (float*)carve(NE * 4);
    unsigned* csum   = (unsigned*)carve(256 * 4);
    unsigned* row_s  = (unsigned*)carve((NN + 1) * 4);
    unsigned* cursor = (unsigned*)carve(NN * 4);
    int*      ecol   = (int*)carve(NE * 4);
    float*    enorm  = (float*)carve(NE * 4);
    float*    bnsum  = (float*)carve(2 * HD * 4);
    float*    scale  = (float*)carve(HD * 4);
    float*    shift  = (float*)carve(HD * 4);
    float*    gsum   = (float*)carve(NG * 4);
    float*    gcnt   = (float*)carve(NG * 4);
    (void)ws_size; (void)n_in; (void)in_sizes; (void)out_size;

    // params
    prep_emb<<<NF + 1, HD, 0, stream>>>(emb, base, delta);

    // degrees & norms
    hipMemsetAsync(deg, 0, NN * 4, stream);
    deg_kernel<<<(NE + 255) / 256, 256, 0, stream>>>(dst, deg, NE);
    dinv_kernel<<<(NN + 255) / 256, 256, 0, stream>>>(deg, dinv, selfn);
    norm_kernel<<<(NE + 255) / 256, 256, 0, stream>>>(src, dst, dinv, norm, NE);

    // CSR build (dst-sorted edge lists)
    chunk_sum<<<NCH, SCAN_CH, 0, stream>>>(deg, csum);
    chunk_scan<<<1, 256, 0, stream>>>(csum, NCH);
    chunk_apply<<<NCH, SCAN_CH, 0, stream>>>(deg, csum, row_s, cursor);
    csr_fill<<<(NE + 255) / 256, 256, 0, stream>>>(src, dst, norm, cursor, ecol, enorm, NE);

    // encoder -> buf0
    atom_encoder<<<2048, 256, 0, stream>>>(x, base, delta, buf0);

    // 3 GCN layers; BN-apply+relu of layer i-1 fused into layer i's GEMM A-load
    for (int i = 0; i < 3; ++i) {
        const float* asc = (i == 0) ? nullptr : scale;
        const float* ash = (i == 0) ? nullptr : shift;
        gemm_f32<<<dim3((NN + 127) / 128, 2), 256, 0, stream>>>(
            buf0, Ws + (size_t)i * HD * HD, buf1, NN, asc, ash);
        gcn_aggregate<<<(NN * 64 + 255) / 256, 256, 0, stream>>>(
            buf1, selfn, bs + i * HD, row_s, ecol, enorm, buf0);
        if (i < 2) {
            hipMemsetAsync(bnsum, 0, 2 * HD * 4, stream);
            bn_stats<<<512, 256, 0, stream>>>(buf0, bnsum);
            bn_finalize<<<1, HD, 0, stream>>>(bnsum, gam + i * HD, bet + i * HD, scale, shift);
        }
    }

    // pool + linear
    hipMemsetAsync(gsum, 0, NG * 4, stream);
    hipMemsetAsync(gcnt, 0, NG * 4, stream);
    pool_dot<<<(NN * 64 + 255) / 256, 256, 0, stream>>>(buf0, lw, batch, gsum, gcnt);
    final_out<<<(NG + 255) / 256, 256, 0, stream>>>(gsum, gcnt, lb, out);
}

// Round 5
// 1153.574 us; speedup vs baseline: 3.1040x; 1.4375x over previous
//
#include <hip/hip_runtime.h>
#include <hip/hip_bf16.h>

#define NN 100000      // nodes
#define NE 200000      // edges
#define NF 56          // atom feats
#define HD 256         // hidden
#define NG 2048        // graphs

#define SCAN_CH 512
#define NCH ((NN + SCAN_CH - 1) / SCAN_CH)   // 196 chunks

// ---- param prep -------------------------------------------------------------
__global__ void prep_emb(const float* __restrict__ emb,
                         float* __restrict__ base, float* __restrict__ delta) {
    int c = threadIdx.x;
    int f = blockIdx.x;
    if (f < NF) {
        float e0 = emb[(f * 2 + 0) * HD + c];
        float e1 = emb[(f * 2 + 1) * HD + c];
        delta[f * HD + c] = e1 - e0;
    } else {
        float s = 0.f;
        for (int ff = 0; ff < NF; ++ff) s += emb[(ff * 2) * HD + c];
        base[c] = s;
    }
}

// dW0[f][c] = sum_k delta[f][k] W0[k][c];  bW0[c] = sum_k base[k] W0[k][c]
__global__ void prep_w0(const float* __restrict__ delta, const float* __restrict__ base,
                        const float* __restrict__ W0,
                        float* __restrict__ dW0, float* __restrict__ bW0) {
    __shared__ float row[HD];
    int c = threadIdx.x;
    int f = blockIdx.x;
    const float* r = (f < NF) ? &delta[f * HD] : base;
    row[c] = r[c];
    __syncthreads();
    float acc = 0.f;
    for (int k = 0; k < HD; ++k) acc += row[k] * W0[k * HD + c];
    if (f < NF) dW0[f * HD + c] = acc; else bW0[c] = acc;
}

// ---- degree / norm ----------------------------------------------------------
__global__ void deg_kernel(const int* __restrict__ dst, unsigned* __restrict__ deg, int E) {
    int e = blockIdx.x * blockDim.x + threadIdx.x;
    if (e < E) atomicAdd(&deg[dst[e]], 1u);
}

__global__ void dinv_kernel(const unsigned* __restrict__ deg, float* __restrict__ dinv,
                            float* __restrict__ selfn) {
    int v = blockIdx.x * blockDim.x + threadIdx.x;
    if (v < NN) {
        float d = (float)(deg[v] + 1u);   // +1 self loop
        dinv[v]  = rsqrtf(d);
        selfn[v] = 1.0f / d;              // dinv^2
    }
}

__global__ void norm_kernel(const int* __restrict__ src, const int* __restrict__ dst,
                            const float* __restrict__ dinv, float* __restrict__ norm, int E) {
    int e = blockIdx.x * blockDim.x + threadIdx.x;
    if (e < E) norm[e] = dinv[src[e]] * dinv[dst[e]];
}

// ---- CSR build: hierarchical exclusive scan of deg + counting-sort fill -----
__global__ void chunk_sum(const unsigned* __restrict__ deg, unsigned* __restrict__ csum) {
    __shared__ unsigned s[SCAN_CH];
    int t = threadIdx.x;
    int base = blockIdx.x * SCAN_CH;
    s[t] = (base + t < NN) ? deg[base + t] : 0u;
    __syncthreads();
    for (int off = SCAN_CH / 2; off > 0; off >>= 1) {
        if (t < off) s[t] += s[t + off];
        __syncthreads();
    }
    if (t == 0) csum[blockIdx.x] = s[0];
}

__global__ void chunk_scan(unsigned* __restrict__ csum, int n) {  // 1 block, 256 thr
    __shared__ unsigned s[256];
    int t = threadIdx.x;
    unsigned v = (t < n) ? csum[t] : 0u;
    s[t] = v;
    __syncthreads();
    for (int off = 1; off < 256; off <<= 1) {
        unsigned add = (t >= off) ? s[t - off] : 0u;
        __syncthreads();
        s[t] += add;
        __syncthreads();
    }
    if (t < n) csum[t] = s[t] - v;   // exclusive
}

__global__ void chunk_apply(const unsigned* __restrict__ deg, const unsigned* __restrict__ csum,
                            unsigned* __restrict__ row_start, unsigned* __restrict__ cursor) {
    __shared__ unsigned s[SCAN_CH];
    int t = threadIdx.x;
    int base = blockIdx.x * SCAN_CH;
    unsigned v = (base + t < NN) ? deg[base + t] : 0u;
    s[t] = v;
    __syncthreads();
    for (int off = 1; off < SCAN_CH; off <<= 1) {
        unsigned add = (t >= off) ? s[t - off] : 0u;
        __syncthreads();
        s[t] += add;
        __syncthreads();
    }
    if (base + t < NN) {
        unsigned rs = csum[blockIdx.x] + s[t] - v;   // exclusive scan value
        row_start[base + t] = rs;
        cursor[base + t] = rs;
    }
    if (blockIdx.x == 0 && t == 0) row_start[NN] = NE;
}

__global__ void csr_fill(const int* __restrict__ src, const int* __restrict__ dst,
                         const float* __restrict__ norm, unsigned* __restrict__ cursor,
                         int* __restrict__ ecol, float* __restrict__ enorm, int E) {
    int e = blockIdx.x * blockDim.x + threadIdx.x;
    if (e < E) {
        unsigned pos = atomicAdd(&cursor[dst[e]], 1u);
        ecol[pos] = src[e];
        enorm[pos] = norm[e];
    }
}

// ---- fused encoder + layer-0 GEMM: hw0[n] = bW0 + sum_{f: x[n][f]=1} dW0[f] -
// One 64-lane wave per node; selection mask distributed via __ballot.
__global__ void __launch_bounds__(256) encoder_gemm(const int* __restrict__ x,
                                                    const float* __restrict__ dW0,
                                                    const float* __restrict__ bW0,
                                                    float* __restrict__ out) {
    __shared__ float tbl[NF * HD];   // 57344 B
    __shared__ float sb[HD];
    int t = threadIdx.x;
    for (int i = t; i < NF * HD / 4; i += 256)
        *(float4*)&tbl[i * 4] = *(const float4*)&dW0[i * 4];
    if (t < HD / 4 * 4 && t < HD) sb[t] = bW0[t];
    __syncthreads();

    int tid = blockIdx.x * 256 + t;
    int n = tid >> 6;
    if (n >= NN) return;
    int l = tid & 63;
    int c4 = l * 4;
    // build 56-bit selection mask, uniform across the wave
    int pred = (l < NF) ? (x[(size_t)n * NF + l] != 0) : 0;
    unsigned long long mask = __ballot(pred);
    float4 acc = *(const float4*)&sb[c4];
    while (mask) {
        int f = __ffsll((long long)mask) - 1;
        mask &= mask - 1;
        float4 u = *(const float4*)&tbl[f * HD + c4];
        acc.x += u.x; acc.y += u.y; acc.z += u.z; acc.w += u.w;
    }
    *(float4*)&out[(size_t)n * HD + c4] = acc;
}

// ---- f32 GEMM: C = relu_bn(A) @ B, 128x128 tile, 8x8/thread -----------------
// ascale/ashift == nullptr -> identity (no BN) on A load.
__global__ void __launch_bounds__(256) gemm_f32(const float* __restrict__ A,
                                                const float* __restrict__ B,
                                                float* __restrict__ C, int M,
                                                const float* __restrict__ ascale,
                                                const float* __restrict__ ashift) {
    __shared__ float sA[8][128];
    __shared__ float sB[8][128];
    int t = threadIdx.x;
    int m0 = blockIdx.x * 128;
    int n0 = blockIdx.y * 128;
    int arow = t >> 1, ak = (t & 1) * 4;
    int brow = t >> 5, bcol = (t & 31) * 4;
    int tm = (t & 15) * 8, tn = (t >> 4) * 8;
    float acc[8][8] = {};
    for (int k0 = 0; k0 < 256; k0 += 8) {
        float4 av = make_float4(0.f, 0.f, 0.f, 0.f);
        if (m0 + arow < M) {
            av = *(const float4*)&A[(size_t)(m0 + arow) * HD + k0 + ak];
            if (ascale) {   // fused batchnorm-apply + relu on the A operand
                av.x = fmaxf(av.x * ascale[k0 + ak + 0] + ashift[k0 + ak + 0], 0.f);
                av.y = fmaxf(av.y * ascale[k0 + ak + 1] + ashift[k0 + ak + 1], 0.f);
                av.z = fmaxf(av.z * ascale[k0 + ak + 2] + ashift[k0 + ak + 2], 0.f);
                av.w = fmaxf(av.w * ascale[k0 + ak + 3] + ashift[k0 + ak + 3], 0.f);
            }
        }
        float4 bv = *(const float4*)&B[(size_t)(k0 + brow) * HD + n0 + bcol];
        __syncthreads();
        sA[ak + 0][arow] = av.x; sA[ak + 1][arow] = av.y;
        sA[ak + 2][arow] = av.z; sA[ak + 3][arow] = av.w;
        *(float4*)&sB[brow][bcol] = bv;
        __syncthreads();
#pragma unroll
        for (int kk = 0; kk < 8; ++kk) {
            float4 a0 = *(const float4*)&sA[kk][tm];
            float4 a1 = *(const float4*)&sA[kk][tm + 4];
            float4 b0 = *(const float4*)&sB[kk][tn];
            float4 b1 = *(const float4*)&sB[kk][tn + 4];
            float a[8] = {a0.x, a0.y, a0.z, a0.w, a1.x, a1.y, a1.z, a1.w};
            float b[8] = {b0.x, b0.y, b0.z, b0.w, b1.x, b1.y, b1.z, b1.w};
#pragma unroll
            for (int i = 0; i < 8; ++i)
#pragma unroll
                for (int j = 0; j < 8; ++j)
                    acc[i][j] += a[i] * b[j];
        }
    }
#pragma unroll
    for (int i = 0; i < 8; ++i) {
        int row = m0 + tm + i;
        if (row < M) {
            *(float4*)&C[(size_t)row * HD + n0 + tn]     = make_float4(acc[i][0], acc[i][1], acc[i][2], acc[i][3]);
            *(float4*)&C[(size_t)row * HD + n0 + tn + 4] = make_float4(acc[i][4], acc[i][5], acc[i][6], acc[i][7]);
        }
    }
}

// ---- CSR gather-aggregate: one 64-lane wave per dst node --------------------
// agg[n] = hw[n]*selfn[n] + bias + sum_{e in CSR[n]} enorm[e] * hw[ecol[e]]
__global__ void __launch_bounds__(256) gcn_aggregate(const float* __restrict__ hw,
                                                     const float* __restrict__ selfn,
                                                     const float* __restrict__ bias,
                                                     const unsigned* __restrict__ row_start,
                                                     const int* __restrict__ ecol,
                                                     const float* __restrict__ enorm,
                                                     float* __restrict__ agg) {
    int tid = blockIdx.x * 256 + threadIdx.x;
    int n = tid >> 6;            // one wave (64 lanes) per node -> uniform edge loop
    if (n >= NN) return;
    int c4 = (tid & 63) * 4;
    float s = selfn[n];
    float4 v = *(const float4*)&hw[(size_t)n * HD + c4];
    float4 acc;
    acc.x = v.x * s + bias[c4 + 0];
    acc.y = v.y * s + bias[c4 + 1];
    acc.z = v.z * s + bias[c4 + 2];
    acc.w = v.w * s + bias[c4 + 3];
    unsigned e0 = row_start[n], e1 = row_start[n + 1];
    for (unsigned e = e0; e < e1; ++e) {
        int sv = ecol[e];
        float nm = enorm[e];
        float4 u = *(const float4*)&hw[(size_t)sv * HD + c4];
        acc.x += u.x * nm;
        acc.y += u.y * nm;
        acc.z += u.z * nm;
        acc.w += u.w * nm;
    }
    *(float4*)&agg[(size_t)n * HD + c4] = acc;
}

// ---- batchnorm stats --------------------------------------------------------
__global__ void bn_stats(const float* __restrict__ h, float* __restrict__ sums) {
    int c = threadIdx.x;
    float s = 0.f, ss = 0.f;
    for (int r = blockIdx.x; r < NN; r += gridDim.x) {
        float v = h[(size_t)r * HD + c];
        s += v; ss += v * v;
    }
    unsafeAtomicAdd(&sums[c], s);
    unsafeAtomicAdd(&sums[HD + c], ss);
}

__global__ void bn_finalize(const float* __restrict__ sums,
                            const float* __restrict__ gamma,
                            const float* __restrict__ beta,
                            float* __restrict__ scale, float* __restrict__ shift) {
    int c = threadIdx.x;
    const float inv_n = 1.0f / (float)NN;
    float mu  = sums[c] * inv_n;
    float var = sums[HD + c] * inv_n - mu * mu;
    float rstd = rsqrtf(var + 1e-5f);
    float sc = gamma[c] * rstd;
    scale[c] = sc;
    shift[c] = beta[c] - mu * sc;
}

// ---- pooling + linear -------------------------------------------------------
__global__ void __launch_bounds__(256) pool_dot(const float* __restrict__ h,
                                                const float* __restrict__ lw,
                                                const int* __restrict__ batch,
                                                float* __restrict__ gsum, float* __restrict__ gcnt) {
    int tid = blockIdx.x * 256 + threadIdx.x;
    int n = tid >> 6;
    if (n >= NN) return;
    int l = tid & 63;
    int c4 = l * 4;
    float4 v = *(const float4*)&h[(size_t)n * HD + c4];
    float s = v.x * lw[c4] + v.y * lw[c4 + 1] + v.z * lw[c4 + 2] + v.w * lw[c4 + 3];
#pragma unroll
    for (int off = 32; off > 0; off >>= 1) s += __shfl_down(s, off, 64);
    if (l == 0) {
        int g = batch[n];
        unsafeAtomicAdd(&gsum[g], s);
        unsafeAtomicAdd(&gcnt[g], 1.0f);
    }
}

__global__ void final_out(const float* __restrict__ gsum, const float* __restrict__ gcnt,
                          const float* __restrict__ lb, float* __restrict__ out) {
    int g = blockIdx.x * blockDim.x + threadIdx.x;
    if (g < NG) {
        float p = gsum[g] / fmaxf(gcnt[g], 1.0f);
        out[g] = p + lb[0];
    }
}

// ---- driver -----------------------------------------------------------------
extern "C" void kernel_launch(void* const* d_in, const int* in_sizes, int n_in,
                              void* d_out, int out_size, void* d_ws, size_t ws_size,
                              hipStream_t stream) {
    const int*   x     = (const int*)d_in[0];
    const int*   ei    = (const int*)d_in[1];
    const int*   batch = (const int*)d_in[2];
    const float* emb   = (const float*)d_in[3];
    const float* Ws    = (const float*)d_in[4];
    const float* bs    = (const float*)d_in[5];
    const float* gam   = (const float*)d_in[6];
    const float* bet   = (const float*)d_in[7];
    const float* lw    = (const float*)d_in[8];
    const float* lb    = (const float*)d_in[9];
    float* out = (float*)d_out;

    const int* src = ei;
    const int* dst = ei + NE;

    // workspace carve-up (256-B aligned)
    char* p = (char*)d_ws;
    size_t off = 0;
    auto carve = [&](size_t bytes) { void* r = p + off; off = (off + bytes + 255) & ~(size_t)255; return r; };
    float*    buf0   = (float*)carve((size_t)NN * HD * 4);
    float*    buf1   = (float*)carve((size_t)NN * HD * 4);
    float*    base   = (float*)carve(HD * 4);
    float*    delta  = (float*)carve(NF * HD * 4);
    float*    dW0    = (float*)carve(NF * HD * 4);
    float*    bW0    = (float*)carve(HD * 4);
    unsigned* deg    = (unsigned*)carve(NN * 4);
    float*    dinv   = (float*)carve(NN * 4);
    float*    selfn  = (float*)carve(NN * 4);
    float*    norm   = (float*)carve(NE * 4);
    unsigned* csum   = (unsigned*)carve(256 * 4);
    unsigned* row_s  = (unsigned*)carve((NN + 1) * 4);
    unsigned* cursor = (unsigned*)carve(NN * 4);
    int*      ecol   = (int*)carve(NE * 4);
    float*    enorm  = (float*)carve(NE * 4);
    float*    bnsum  = (float*)carve(2 * HD * 4);
    float*    scale  = (float*)carve(HD * 4);
    float*    shift  = (float*)carve(HD * 4);
    float*    gsum   = (float*)carve(NG * 4);
    float*    gcnt   = (float*)carve(NG * 4);
    (void)ws_size; (void)n_in; (void)in_sizes; (void)out_size;

    // params
    prep_emb<<<NF + 1, HD, 0, stream>>>(emb, base, delta);
    prep_w0<<<NF + 1, HD, 0, stream>>>(delta, base, Ws, dW0, bW0);

    // degrees & norms
    hipMemsetAsync(deg, 0, NN * 4, stream);
    deg_kernel<<<(NE + 255) / 256, 256, 0, stream>>>(dst, deg, NE);
    dinv_kernel<<<(NN + 255) / 256, 256, 0, stream>>>(deg, dinv, selfn);
    norm_kernel<<<(NE + 255) / 256, 256, 0, stream>>>(src, dst, dinv, norm, NE);

    // CSR build (dst-sorted edge lists)
    chunk_sum<<<NCH, SCAN_CH, 0, stream>>>(deg, csum);
    chunk_scan<<<1, 256, 0, stream>>>(csum, NCH);
    chunk_apply<<<NCH, SCAN_CH, 0, stream>>>(deg, csum, row_s, cursor);
    csr_fill<<<(NE + 255) / 256, 256, 0, stream>>>(src, dst, norm, cursor, ecol, enorm, NE);

    // layer 0: fused encoder+GEMM -> buf1 (hw0), then aggregate -> buf0
    encoder_gemm<<<(NN * 64 + 255) / 256, 256, 0, stream>>>(x, dW0, bW0, buf1);
    gcn_aggregate<<<(NN * 64 + 255) / 256, 256, 0, stream>>>(
        buf1, selfn, bs, row_s, ecol, enorm, buf0);
    hipMemsetAsync(bnsum, 0, 2 * HD * 4, stream);
    bn_stats<<<512, 256, 0, stream>>>(buf0, bnsum);
    bn_finalize<<<1, HD, 0, stream>>>(bnsum, gam, bet, scale, shift);

    // layers 1,2: BN-apply+relu fused into GEMM A-load
    for (int i = 1; i < 3; ++i) {
        gemm_f32<<<dim3((NN + 127) / 128, 2), 256, 0, stream>>>(
            buf0, Ws + (size_t)i * HD * HD, buf1, NN, scale, shift);
        gcn_aggregate<<<(NN * 64 + 255) / 256, 256, 0, stream>>>(
            buf1, selfn, bs + i * HD, row_s, ecol, enorm, buf0);
        if (i < 2) {
            hipMemsetAsync(bnsum, 0, 2 * HD * 4, stream);
            bn_stats<<<512, 256, 0, stream>>>(buf0, bnsum);
            bn_finalize<<<1, HD, 0, stream>>>(bnsum, gam + i * HD, bet + i * HD, scale, shift);
        }
    }

    // pool + linear
    hipMemsetAsync(gsum, 0, NG * 4, stream);
    hipMemsetAsync(gcnt, 0, NG * 4, stream);
    pool_dot<<<(NN * 64 + 255) / 256, 256, 0, stream>>>(buf0, lw, batch, gsum, gcnt);
    final_out<<<(NG + 255) / 256, 256, 0, stream>>>(gsum, gcnt, lb, out);
}

// Round 6
// 832.226 us; speedup vs baseline: 4.3026x; 1.3861x over previous
//
#include <hip/hip_runtime.h>
#include <hip/hip_bf16.h>

#define NN 100000      // nodes
#define NE 200000      // edges
#define NF 56          // atom feats
#define HD 256         // hidden
#define NG 2048        // graphs

#define SCAN_CH 512
#define NCH ((NN + SCAN_CH - 1) / SCAN_CH)   // 196 chunks

typedef __bf16 bf16x8 __attribute__((ext_vector_type(8)));
typedef __bf16 bf16x4 __attribute__((ext_vector_type(4)));
typedef float  floatx4 __attribute__((ext_vector_type(4)));

// ---- param prep -------------------------------------------------------------
__global__ void prep_emb(const float* __restrict__ emb,
                         float* __restrict__ base, float* __restrict__ delta) {
    int c = threadIdx.x;
    int f = blockIdx.x;
    if (f < NF) {
        float e0 = emb[(f * 2 + 0) * HD + c];
        float e1 = emb[(f * 2 + 1) * HD + c];
        delta[f * HD + c] = e1 - e0;
    } else {
        float s = 0.f;
        for (int ff = 0; ff < NF; ++ff) s += emb[(ff * 2) * HD + c];
        base[c] = s;
    }
}

// dW0[f][c] = sum_k delta[f][k] W0[k][c];  bW0[c] = sum_k base[k] W0[k][c]
__global__ void prep_w0(const float* __restrict__ delta, const float* __restrict__ base,
                        const float* __restrict__ W0,
                        float* __restrict__ dW0, float* __restrict__ bW0) {
    __shared__ float row[HD];
    int c = threadIdx.x;
    int f = blockIdx.x;
    const float* r = (f < NF) ? &delta[f * HD] : base;
    row[c] = r[c];
    __syncthreads();
    float acc = 0.f;
    for (int k = 0; k < HD; ++k) acc += row[k] * W0[k * HD + c];
    if (f < NF) dW0[f * HD + c] = acc; else bW0[c] = acc;
}

// Wt[l][n][k] = bf16(Ws[l+1][k][n])  -- transposed bf16 weights for layers 1,2
__global__ void cvt_w(const float* __restrict__ Ws, __bf16* __restrict__ Wt) {
    int n = blockIdx.x, l = blockIdx.y, k = threadIdx.x;
    Wt[((size_t)l * HD + n) * HD + k] = (__bf16)Ws[(size_t)(l + 1) * HD * HD + (size_t)k * HD + n];
}

// ---- degree / norm ----------------------------------------------------------
__global__ void deg_kernel(const int* __restrict__ dst, unsigned* __restrict__ deg, int E) {
    int e = blockIdx.x * blockDim.x + threadIdx.x;
    if (e < E) atomicAdd(&deg[dst[e]], 1u);
}

__global__ void dinv_kernel(const unsigned* __restrict__ deg, float* __restrict__ dinv,
                            float* __restrict__ selfn) {
    int v = blockIdx.x * blockDim.x + threadIdx.x;
    if (v < NN) {
        float d = (float)(deg[v] + 1u);   // +1 self loop
        dinv[v]  = rsqrtf(d);
        selfn[v] = 1.0f / d;              // dinv^2
    }
}

__global__ void norm_kernel(const int* __restrict__ src, const int* __restrict__ dst,
                            const float* __restrict__ dinv, float* __restrict__ norm, int E) {
    int e = blockIdx.x * blockDim.x + threadIdx.x;
    if (e < E) norm[e] = dinv[src[e]] * dinv[dst[e]];
}

// ---- CSR build: hierarchical exclusive scan of deg + counting-sort fill -----
__global__ void chunk_sum(const unsigned* __restrict__ deg, unsigned* __restrict__ csum) {
    __shared__ unsigned s[SCAN_CH];
    int t = threadIdx.x;
    int base = blockIdx.x * SCAN_CH;
    s[t] = (base + t < NN) ? deg[base + t] : 0u;
    __syncthreads();
    for (int off = SCAN_CH / 2; off > 0; off >>= 1) {
        if (t < off) s[t] += s[t + off];
        __syncthreads();
    }
    if (t == 0) csum[blockIdx.x] = s[0];
}

__global__ void chunk_scan(unsigned* __restrict__ csum, int n) {  // 1 block, 256 thr
    __shared__ unsigned s[256];
    int t = threadIdx.x;
    unsigned v = (t < n) ? csum[t] : 0u;
    s[t] = v;
    __syncthreads();
    for (int off = 1; off < 256; off <<= 1) {
        unsigned add = (t >= off) ? s[t - off] : 0u;
        __syncthreads();
        s[t] += add;
        __syncthreads();
    }
    if (t < n) csum[t] = s[t] - v;   // exclusive
}

__global__ void chunk_apply(const unsigned* __restrict__ deg, const unsigned* __restrict__ csum,
                            unsigned* __restrict__ row_start, unsigned* __restrict__ cursor) {
    __shared__ unsigned s[SCAN_CH];
    int t = threadIdx.x;
    int base = blockIdx.x * SCAN_CH;
    unsigned v = (base + t < NN) ? deg[base + t] : 0u;
    s[t] = v;
    __syncthreads();
    for (int off = 1; off < SCAN_CH; off <<= 1) {
        unsigned add = (t >= off) ? s[t - off] : 0u;
        __syncthreads();
        s[t] += add;
        __syncthreads();
    }
    if (base + t < NN) {
        unsigned rs = csum[blockIdx.x] + s[t] - v;   // exclusive scan value
        row_start[base + t] = rs;
        cursor[base + t] = rs;
    }
    if (blockIdx.x == 0 && t == 0) row_start[NN] = NE;
}

__global__ void csr_fill(const int* __restrict__ src, const int* __restrict__ dst,
                         const float* __restrict__ norm, unsigned* __restrict__ cursor,
                         int* __restrict__ ecol, float* __restrict__ enorm, int E) {
    int e = blockIdx.x * blockDim.x + threadIdx.x;
    if (e < E) {
        unsigned pos = atomicAdd(&cursor[dst[e]], 1u);
        ecol[pos] = src[e];
        enorm[pos] = norm[e];
    }
}

// ---- fused encoder + layer-0 GEMM: hw0[n] = bW0 + sum_{f: x[n][f]=1} dW0[f] -
__global__ void __launch_bounds__(256) encoder_gemm(const int* __restrict__ x,
                                                    const float* __restrict__ dW0,
                                                    const float* __restrict__ bW0,
                                                    float* __restrict__ out) {
    __shared__ float tbl[NF * HD];   // 57344 B
    __shared__ float sb[HD];
    int t = threadIdx.x;
    for (int i = t; i < NF * HD / 4; i += 256)
        *(float4*)&tbl[i * 4] = *(const float4*)&dW0[i * 4];
    if (t < HD) sb[t] = bW0[t];
    __syncthreads();

    int tid = blockIdx.x * 256 + t;
    int n = tid >> 6;
    if (n >= NN) return;
    int l = tid & 63;
    int c4 = l * 4;
    int pred = (l < NF) ? (x[(size_t)n * NF + l] != 0) : 0;
    unsigned long long mask = __ballot(pred);
    float4 acc = *(const float4*)&sb[c4];
    while (mask) {
        int f = __ffsll((long long)mask) - 1;
        mask &= mask - 1;
        float4 u = *(const float4*)&tbl[f * HD + c4];
        acc.x += u.x; acc.y += u.y; acc.z += u.z; acc.w += u.w;
    }
    *(float4*)&out[(size_t)n * HD + c4] = acc;
}

// ---- bf16 MFMA GEMM: C[M,256] = relu_bn(A) @ W, 128x128 tile ----------------
// A: f32 [M,256]; Wt: bf16 [256 n][256 k] (pre-transposed); C: f32.
// BN scale/shift + relu fused into the A-operand staging.
#define LSTR 40   // LDS row stride in bf16 (32 data + 8 pad -> 2-way-free banks)
__global__ void __launch_bounds__(256) gemm_mfma(const float* __restrict__ A,
                                                 const __bf16* __restrict__ Wt,
                                                 float* __restrict__ C, int M,
                                                 const float* __restrict__ ascale,
                                                 const float* __restrict__ ashift) {
    __shared__ __bf16 sA[128 * LSTR];   // 10240 B
    __shared__ __bf16 sB[128 * LSTR];   // 10240 B
    int t = threadIdx.x;
    int m0 = blockIdx.x * 128;
    int n0 = blockIdx.y * 128;
    int lane = t & 63, w = t >> 6;
    int quad = lane >> 4, l16 = lane & 15;
    int mw = (w & 1) * 64, nw = (w >> 1) * 64;

    int ar = t >> 3;          // A-stage: rows ar, ar+32, ar+64, ar+96
    int ak = (t & 7) * 4;     // k-offset within 32-tile
    int bn = t >> 1;          // B-stage: LDS row (n)
    int bk = (t & 1) * 16;    // k-offset

    floatx4 acc[4][4] = {};

    for (int k0 = 0; k0 < 256; k0 += 32) {
        // BN params for this thread's 4 staged columns (same for all 4 row-passes)
        float4 sc = *(const float4*)&ascale[k0 + ak];
        float4 sh = *(const float4*)&ashift[k0 + ak];
        #pragma unroll
        for (int p = 0; p < 4; ++p) {
            int r = p * 32 + ar;
            int row = m0 + r;
            float4 v = make_float4(0.f, 0.f, 0.f, 0.f);
            if (row < M) v = *(const float4*)&A[(size_t)row * HD + k0 + ak];
            v.x = fmaxf(v.x * sc.x + sh.x, 0.f);
            v.y = fmaxf(v.y * sc.y + sh.y, 0.f);
            v.z = fmaxf(v.z * sc.z + sh.z, 0.f);
            v.w = fmaxf(v.w * sc.w + sh.w, 0.f);
            bf16x4 b;
            b[0] = (__bf16)v.x; b[1] = (__bf16)v.y; b[2] = (__bf16)v.z; b[3] = (__bf16)v.w;
            *(bf16x4*)&sA[r * LSTR + ak] = b;
        }
        #pragma unroll
        for (int j = 0; j < 2; ++j) {
            bf16x8 v = *(const bf16x8*)&Wt[(size_t)(n0 + bn) * HD + k0 + bk + j * 8];
            *(bf16x8*)&sB[bn * LSTR + bk + j * 8] = v;
        }
        __syncthreads();

        bf16x8 af[4], bf[4];
        #pragma unroll
        for (int i = 0; i < 4; ++i)
            af[i] = *(const bf16x8*)&sA[(mw + i * 16 + l16) * LSTR + quad * 8];
        #pragma unroll
        for (int i = 0; i < 4; ++i)
            bf[i] = *(const bf16x8*)&sB[(nw + i * 16 + l16) * LSTR + quad * 8];
        #pragma unroll
        for (int mi = 0; mi < 4; ++mi)
            #pragma unroll
            for (int ni = 0; ni < 4; ++ni)
                acc[mi][ni] = __builtin_amdgcn_mfma_f32_16x16x32_bf16(
                    af[mi], bf[ni], acc[mi][ni], 0, 0, 0);
        __syncthreads();
    }

    // epilogue: C/D layout col=lane&15, row=quad*4+reg
    #pragma unroll
    for (int mi = 0; mi < 4; ++mi) {
        #pragma unroll
        for (int r = 0; r < 4; ++r) {
            int row = m0 + mw + mi * 16 + quad * 4 + r;
            if (row < M) {
                #pragma unroll
                for (int ni = 0; ni < 4; ++ni)
                    C[(size_t)row * HD + n0 + nw + ni * 16 + l16] = acc[mi][ni][r];
            }
        }
    }
}

// ---- CSR gather-aggregate: one 64-lane wave per dst node --------------------
__global__ void __launch_bounds__(256) gcn_aggregate(const float* __restrict__ hw,
                                                     const float* __restrict__ selfn,
                                                     const float* __restrict__ bias,
                                                     const unsigned* __restrict__ row_start,
                                                     const int* __restrict__ ecol,
                                                     const float* __restrict__ enorm,
                                                     float* __restrict__ agg) {
    int tid = blockIdx.x * 256 + threadIdx.x;
    int n = tid >> 6;            // one wave (64 lanes) per node -> uniform edge loop
    if (n >= NN) return;
    int c4 = (tid & 63) * 4;
    float s = selfn[n];
    float4 v = *(const float4*)&hw[(size_t)n * HD + c4];
    float4 acc;
    acc.x = v.x * s + bias[c4 + 0];
    acc.y = v.y * s + bias[c4 + 1];
    acc.z = v.z * s + bias[c4 + 2];
    acc.w = v.w * s + bias[c4 + 3];
    unsigned e0 = row_start[n], e1 = row_start[n + 1];
    for (unsigned e = e0; e < e1; ++e) {
        int sv = ecol[e];
        float nm = enorm[e];
        float4 u = *(const float4*)&hw[(size_t)sv * HD + c4];
        acc.x += u.x * nm;
        acc.y += u.y * nm;
        acc.z += u.z * nm;
        acc.w += u.w * nm;
    }
    *(float4*)&agg[(size_t)n * HD + c4] = acc;
}

// ---- batchnorm stats --------------------------------------------------------
__global__ void bn_stats(const float* __restrict__ h, float* __restrict__ sums) {
    int c = threadIdx.x;
    float s = 0.f, ss = 0.f;
    for (int r = blockIdx.x; r < NN; r += gridDim.x) {
        float v = h[(size_t)r * HD + c];
        s += v; ss += v * v;
    }
    unsafeAtomicAdd(&sums[c], s);
    unsafeAtomicAdd(&sums[HD + c], ss);
}

__global__ void bn_finalize(const float* __restrict__ sums,
                            const float* __restrict__ gamma,
                            const float* __restrict__ beta,
                            float* __restrict__ scale, float* __restrict__ shift) {
    int c = threadIdx.x;
    const float inv_n = 1.0f / (float)NN;
    float mu  = sums[c] * inv_n;
    float var = sums[HD + c] * inv_n - mu * mu;
    float rstd = rsqrtf(var + 1e-5f);
    float sc = gamma[c] * rstd;
    scale[c] = sc;
    shift[c] = beta[c] - mu * sc;
}

// ---- pooling + linear -------------------------------------------------------
__global__ void __launch_bounds__(256) pool_dot(const float* __restrict__ h,
                                                const float* __restrict__ lw,
                                                const int* __restrict__ batch,
                                                float* __restrict__ gsum, float* __restrict__ gcnt) {
    int tid = blockIdx.x * 256 + threadIdx.x;
    int n = tid >> 6;
    if (n >= NN) return;
    int l = tid & 63;
    int c4 = l * 4;
    float4 v = *(const float4*)&h[(size_t)n * HD + c4];
    float s = v.x * lw[c4] + v.y * lw[c4 + 1] + v.z * lw[c4 + 2] + v.w * lw[c4 + 3];
#pragma unroll
    for (int off = 32; off > 0; off >>= 1) s += __shfl_down(s, off, 64);
    if (l == 0) {
        int g = batch[n];
        unsafeAtomicAdd(&gsum[g], s);
        unsafeAtomicAdd(&gcnt[g], 1.0f);
    }
}

__global__ void final_out(const float* __restrict__ gsum, const float* __restrict__ gcnt,
                          const float* __restrict__ lb, float* __restrict__ out) {
    int g = blockIdx.x * blockDim.x + threadIdx.x;
    if (g < NG) {
        float p = gsum[g] / fmaxf(gcnt[g], 1.0f);
        out[g] = p + lb[0];
    }
}

// ---- driver -----------------------------------------------------------------
extern "C" void kernel_launch(void* const* d_in, const int* in_sizes, int n_in,
                              void* d_out, int out_size, void* d_ws, size_t ws_size,
                              hipStream_t stream) {
    const int*   x     = (const int*)d_in[0];
    const int*   ei    = (const int*)d_in[1];
    const int*   batch = (const int*)d_in[2];
    const float* emb   = (const float*)d_in[3];
    const float* Ws    = (const float*)d_in[4];
    const float* bs    = (const float*)d_in[5];
    const float* gam   = (const float*)d_in[6];
    const float* bet   = (const float*)d_in[7];
    const float* lw    = (const float*)d_in[8];
    const float* lb    = (const float*)d_in[9];
    float* out = (float*)d_out;

    const int* src = ei;
    const int* dst = ei + NE;

    // workspace carve-up (256-B aligned)
    char* p = (char*)d_ws;
    size_t off = 0;
    auto carve = [&](size_t bytes) { void* r = p + off; off = (off + bytes + 255) & ~(size_t)255; return r; };
    float*    buf0   = (float*)carve((size_t)NN * HD * 4);
    float*    buf1   = (float*)carve((size_t)NN * HD * 4);
    float*    base   = (float*)carve(HD * 4);
    float*    delta  = (float*)carve(NF * HD * 4);
    float*    dW0    = (float*)carve(NF * HD * 4);
    float*    bW0    = (float*)carve(HD * 4);
    __bf16*   Wt     = (__bf16*)carve((size_t)2 * HD * HD * 2);
    unsigned* deg    = (unsigned*)carve(NN * 4);
    float*    dinv   = (float*)carve(NN * 4);
    float*    selfn  = (float*)carve(NN * 4);
    float*    norm   = (float*)carve(NE * 4);
    unsigned* csum   = (unsigned*)carve(256 * 4);
    unsigned* row_s  = (unsigned*)carve((NN + 1) * 4);
    unsigned* cursor = (unsigned*)carve(NN * 4);
    int*      ecol   = (int*)carve(NE * 4);
    float*    enorm  = (float*)carve(NE * 4);
    float*    bnsum  = (float*)carve(2 * HD * 4);
    float*    scale  = (float*)carve(HD * 4);
    float*    shift  = (float*)carve(HD * 4);
    float*    gsum   = (float*)carve(NG * 4);
    float*    gcnt   = (float*)carve(NG * 4);
    (void)ws_size; (void)n_in; (void)in_sizes; (void)out_size;

    // params
    prep_emb<<<NF + 1, HD, 0, stream>>>(emb, base, delta);
    prep_w0<<<NF + 1, HD, 0, stream>>>(delta, base, Ws, dW0, bW0);
    cvt_w<<<dim3(HD, 2), HD, 0, stream>>>(Ws, Wt);

    // degrees & norms
    hipMemsetAsync(deg, 0, NN * 4, stream);
    deg_kernel<<<(NE + 255) / 256, 256, 0, stream>>>(dst, deg, NE);
    dinv_kernel<<<(NN + 255) / 256, 256, 0, stream>>>(deg, dinv, selfn);
    norm_kernel<<<(NE + 255) / 256, 256, 0, stream>>>(src, dst, dinv, norm, NE);

    // CSR build (dst-sorted edge lists)
    chunk_sum<<<NCH, SCAN_CH, 0, stream>>>(deg, csum);
    chunk_scan<<<1, 256, 0, stream>>>(csum, NCH);
    chunk_apply<<<NCH, SCAN_CH, 0, stream>>>(deg, csum, row_s, cursor);
    csr_fill<<<(NE + 255) / 256, 256, 0, stream>>>(src, dst, norm, cursor, ecol, enorm, NE);

    // layer 0: fused encoder+GEMM -> buf1 (hw0), then aggregate -> buf0
    encoder_gemm<<<(NN * 64 + 255) / 256, 256, 0, stream>>>(x, dW0, bW0, buf1);
    gcn_aggregate<<<(NN * 64 + 255) / 256, 256, 0, stream>>>(
        buf1, selfn, bs, row_s, ecol, enorm, buf0);
    hipMemsetAsync(bnsum, 0, 2 * HD * 4, stream);
    bn_stats<<<512, 256, 0, stream>>>(buf0, bnsum);
    bn_finalize<<<1, HD, 0, stream>>>(bnsum, gam, bet, scale, shift);

    // layers 1,2: MFMA GEMM with fused BN-apply+relu on A
    for (int i = 1; i < 3; ++i) {
        gemm_mfma<<<dim3((NN + 127) / 128, 2), 256, 0, stream>>>(
            buf0, Wt + (size_t)(i - 1) * HD * HD, buf1, NN, scale, shift);
        gcn_aggregate<<<(NN * 64 + 255) / 256, 256, 0, stream>>>(
            buf1, selfn, bs + i * HD, row_s, ecol, enorm, buf0);
        if (i < 2) {
            hipMemsetAsync(bnsum, 0, 2 * HD * 4, stream);
            bn_stats<<<512, 256, 0, stream>>>(buf0, bnsum);
            bn_finalize<<<1, HD, 0, stream>>>(bnsum, gam + i * HD, bet + i * HD, scale, shift);
        }
    }

    // pool + linear
    hipMemsetAsync(gsum, 0, NG * 4, stream);
    hipMemsetAsync(gcnt, 0, NG * 4, stream);
    pool_dot<<<(NN * 64 + 255) / 256, 256, 0, stream>>>(buf0, lw, batch, gsum, gcnt);
    final_out<<<(NG + 255) / 256, 256, 0, stream>>>(gsum, gcnt, lb, out);
}

// Round 7
// 665.256 us; speedup vs baseline: 5.3825x; 1.2510x over previous
//
#include <hip/hip_runtime.h>
#include <hip/hip_bf16.h>

#define NN 100000      // nodes
#define NE 200000      // edges
#define NF 56          // atom feats
#define HD 256         // hidden
#define NG 2048        // graphs

#define SCAN_CH 512
#define NCH ((NN + SCAN_CH - 1) / SCAN_CH)   // 196 chunks

typedef __bf16 bf16x8 __attribute__((ext_vector_type(8)));
typedef __bf16 bf16x4 __attribute__((ext_vector_type(4)));
typedef float  floatx4 __attribute__((ext_vector_type(4)));

// ---- param prep -------------------------------------------------------------
__global__ void prep_emb(const float* __restrict__ emb,
                         float* __restrict__ base, float* __restrict__ delta) {
    int c = threadIdx.x;
    int f = blockIdx.x;
    if (f < NF) {
        float e0 = emb[(f * 2 + 0) * HD + c];
        float e1 = emb[(f * 2 + 1) * HD + c];
        delta[f * HD + c] = e1 - e0;
    } else {
        float s = 0.f;
        for (int ff = 0; ff < NF; ++ff) s += emb[(ff * 2) * HD + c];
        base[c] = s;
    }
}

// dW0[f][c] = sum_k delta[f][k] W0[k][c];  bW0[c] = sum_k base[k] W0[k][c]
__global__ void prep_w0(const float* __restrict__ delta, const float* __restrict__ base,
                        const float* __restrict__ W0,
                        float* __restrict__ dW0, float* __restrict__ bW0) {
    __shared__ float row[HD];
    int c = threadIdx.x;
    int f = blockIdx.x;
    const float* r = (f < NF) ? &delta[f * HD] : base;
    row[c] = r[c];
    __syncthreads();
    float acc = 0.f;
    for (int k = 0; k < HD; ++k) acc += row[k] * W0[k * HD + c];
    if (f < NF) dW0[f * HD + c] = acc; else bW0[c] = acc;
}

// dW0t[n][k] = bf16(dW0[k][n]), zero-padded K 56->64
__global__ void prep_w0t(const float* __restrict__ dW0, __bf16* __restrict__ dW0t) {
    int n = blockIdx.x;       // 256
    int k = threadIdx.x;      // 64
    dW0t[n * 64 + k] = (k < NF) ? (__bf16)dW0[k * HD + n] : (__bf16)0.f;
}

// Wt[l][n][k] = bf16(Ws[l+1][k][n])  -- transposed bf16 weights for layers 1,2
__global__ void cvt_w(const float* __restrict__ Ws, __bf16* __restrict__ Wt) {
    int n = blockIdx.x, l = blockIdx.y, k = threadIdx.x;
    Wt[((size_t)l * HD + n) * HD + k] = (__bf16)Ws[(size_t)(l + 1) * HD * HD + (size_t)k * HD + n];
}

// ---- degree / norm ----------------------------------------------------------
__global__ void deg_kernel(const int* __restrict__ dst, unsigned* __restrict__ deg, int E) {
    int e = blockIdx.x * blockDim.x + threadIdx.x;
    if (e < E) atomicAdd(&deg[dst[e]], 1u);
}

__global__ void dinv_kernel(const unsigned* __restrict__ deg, float* __restrict__ dinv,
                            float* __restrict__ selfn) {
    int v = blockIdx.x * blockDim.x + threadIdx.x;
    if (v < NN) {
        float d = (float)(deg[v] + 1u);   // +1 self loop
        dinv[v]  = rsqrtf(d);
        selfn[v] = 1.0f / d;              // dinv^2
    }
}

__global__ void norm_kernel(const int* __restrict__ src, const int* __restrict__ dst,
                            const float* __restrict__ dinv, float* __restrict__ norm, int E) {
    int e = blockIdx.x * blockDim.x + threadIdx.x;
    if (e < E) norm[e] = dinv[src[e]] * dinv[dst[e]];
}

// ---- CSR build: hierarchical exclusive scan of deg + counting-sort fill -----
__global__ void chunk_sum(const unsigned* __restrict__ deg, unsigned* __restrict__ csum) {
    __shared__ unsigned s[SCAN_CH];
    int t = threadIdx.x;
    int base = blockIdx.x * SCAN_CH;
    s[t] = (base + t < NN) ? deg[base + t] : 0u;
    __syncthreads();
    for (int off = SCAN_CH / 2; off > 0; off >>= 1) {
        if (t < off) s[t] += s[t + off];
        __syncthreads();
    }
    if (t == 0) csum[blockIdx.x] = s[0];
}

__global__ void chunk_scan(unsigned* __restrict__ csum, int n) {  // 1 block, 256 thr
    __shared__ unsigned s[256];
    int t = threadIdx.x;
    unsigned v = (t < n) ? csum[t] : 0u;
    s[t] = v;
    __syncthreads();
    for (int off = 1; off < 256; off <<= 1) {
        unsigned add = (t >= off) ? s[t - off] : 0u;
        __syncthreads();
        s[t] += add;
        __syncthreads();
    }
    if (t < n) csum[t] = s[t] - v;   // exclusive
}

__global__ void chunk_apply(const unsigned* __restrict__ deg, const unsigned* __restrict__ csum,
                            unsigned* __restrict__ row_start, unsigned* __restrict__ cursor) {
    __shared__ unsigned s[SCAN_CH];
    int t = threadIdx.x;
    int base = blockIdx.x * SCAN_CH;
    unsigned v = (base + t < NN) ? deg[base + t] : 0u;
    s[t] = v;
    __syncthreads();
    for (int off = 1; off < SCAN_CH; off <<= 1) {
        unsigned add = (t >= off) ? s[t - off] : 0u;
        __syncthreads();
        s[t] += add;
        __syncthreads();
    }
    if (base + t < NN) {
        unsigned rs = csum[blockIdx.x] + s[t] - v;   // exclusive scan value
        row_start[base + t] = rs;
        cursor[base + t] = rs;
    }
    if (blockIdx.x == 0 && t == 0) row_start[NN] = NE;
}

__global__ void csr_fill(const int* __restrict__ src, const int* __restrict__ dst,
                         const float* __restrict__ norm, unsigned* __restrict__ cursor,
                         int* __restrict__ ecol, float* __restrict__ enorm, int E) {
    int e = blockIdx.x * blockDim.x + threadIdx.x;
    if (e < E) {
        unsigned pos = atomicAdd(&cursor[dst[e]], 1u);
        ecol[pos] = src[e];
        enorm[pos] = norm[e];
    }
}

// ---- MFMA encoder: hw0 = X @ dW0t^T + bW0, X binary [NN,56] pad K->64 -------
// 128x128 tile, 4 waves 2x2, each wave 64x64 via 4x4 mfma 16x16x32.
#define ELSTR 72   // LDS row stride (64 + 8 pad) in bf16
__global__ void __launch_bounds__(256) encoder_mfma(const int* __restrict__ x,
                                                    const __bf16* __restrict__ dW0t,
                                                    const float* __restrict__ bW0,
                                                    float* __restrict__ C) {
    __shared__ __bf16 sA[128 * ELSTR];   // 18432 B
    __shared__ __bf16 sB[128 * ELSTR];   // 18432 B
    int t = threadIdx.x;
    int m0 = blockIdx.x * 128;
    int n0 = blockIdx.y * 128;
    int lane = t & 63, w = t >> 6;
    int quad = lane >> 4, l16 = lane & 15;
    int mw = (w & 1) * 64, nw = (w >> 1) * 64;

    // A-stage: 2 threads/row; convert x ints (0/1, exact in bf16) on the fly
    {
        int r = t >> 1;
        int kh = (t & 1) * 32;
        int row = m0 + r;
        int nreal = (kh == 0) ? 32 : 24;   // real features in this k-half
        #pragma unroll
        for (int j = 0; j < 8; ++j) {
            bf16x4 b;
            if (row < NN && j * 4 < nreal) {
                int4 iv = *(const int4*)&x[(size_t)row * NF + kh + j * 4];
                b[0] = (__bf16)(float)iv.x;
                b[1] = (__bf16)(float)iv.y;
                b[2] = (__bf16)(float)iv.z;
                b[3] = (__bf16)(float)iv.w;
            } else {
                b[0] = b[1] = b[2] = b[3] = (__bf16)0.f;
            }
            *(bf16x4*)&sA[r * ELSTR + kh + j * 4] = b;
        }
    }
    // B-stage: dW0t [256 n][64 k] bf16
    {
        int bn = t >> 1;
        int kh = (t & 1) * 32;
        #pragma unroll
        for (int j = 0; j < 4; ++j) {
            bf16x8 v = *(const bf16x8*)&dW0t[(size_t)(n0 + bn) * 64 + kh + j * 8];
            *(bf16x8*)&sB[bn * ELSTR + kh + j * 8] = v;
        }
    }
    __syncthreads();

    floatx4 acc[4][4] = {};
    #pragma unroll
    for (int s = 0; s < 2; ++s) {
        bf16x8 af[4], bfr[4];
        #pragma unroll
        for (int i = 0; i < 4; ++i)
            af[i] = *(const bf16x8*)&sA[(mw + i * 16 + l16) * ELSTR + s * 32 + quad * 8];
        #pragma unroll
        for (int i = 0; i < 4; ++i)
            bfr[i] = *(const bf16x8*)&sB[(nw + i * 16 + l16) * ELSTR + s * 32 + quad * 8];
        #pragma unroll
        for (int mi = 0; mi < 4; ++mi)
            #pragma unroll
            for (int ni = 0; ni < 4; ++ni)
                acc[mi][ni] = __builtin_amdgcn_mfma_f32_16x16x32_bf16(
                    af[mi], bfr[ni], acc[mi][ni], 0, 0, 0);
    }

    // epilogue: add bW0 broadcast; C/D layout col=lane&15, row=quad*4+reg
    float bw[4];
    #pragma unroll
    for (int ni = 0; ni < 4; ++ni) bw[ni] = bW0[n0 + nw + ni * 16 + l16];
    #pragma unroll
    for (int mi = 0; mi < 4; ++mi) {
        #pragma unroll
        for (int r = 0; r < 4; ++r) {
            int row = m0 + mw + mi * 16 + quad * 4 + r;
            if (row < NN) {
                #pragma unroll
                for (int ni = 0; ni < 4; ++ni)
                    C[(size_t)row * HD + n0 + nw + ni * 16 + l16] = acc[mi][ni][r] + bw[ni];
            }
        }
    }
}

// ---- bf16 MFMA GEMM: C[M,256] = relu_bn(A) @ W, 128x128 tile ----------------
#define LSTR 40   // LDS row stride in bf16 (32 data + 8 pad)
__global__ void __launch_bounds__(256) gemm_mfma(const float* __restrict__ A,
                                                 const __bf16* __restrict__ Wt,
                                                 float* __restrict__ C, int M,
                                                 const float* __restrict__ ascale,
                                                 const float* __restrict__ ashift) {
    __shared__ __bf16 sA[128 * LSTR];   // 10240 B
    __shared__ __bf16 sB[128 * LSTR];   // 10240 B
    int t = threadIdx.x;
    int m0 = blockIdx.x * 128;
    int n0 = blockIdx.y * 128;
    int lane = t & 63, w = t >> 6;
    int quad = lane >> 4, l16 = lane & 15;
    int mw = (w & 1) * 64, nw = (w >> 1) * 64;

    int ar = t >> 3;          // A-stage: rows ar, ar+32, ar+64, ar+96
    int ak = (t & 7) * 4;     // k-offset within 32-tile
    int bn = t >> 1;          // B-stage: LDS row (n)
    int bk = (t & 1) * 16;    // k-offset

    floatx4 acc[4][4] = {};

    for (int k0 = 0; k0 < 256; k0 += 32) {
        float4 sc = *(const float4*)&ascale[k0 + ak];
        float4 sh = *(const float4*)&ashift[k0 + ak];
        #pragma unroll
        for (int p = 0; p < 4; ++p) {
            int r = p * 32 + ar;
            int row = m0 + r;
            float4 v = make_float4(0.f, 0.f, 0.f, 0.f);
            if (row < M) v = *(const float4*)&A[(size_t)row * HD + k0 + ak];
            v.x = fmaxf(v.x * sc.x + sh.x, 0.f);
            v.y = fmaxf(v.y * sc.y + sh.y, 0.f);
            v.z = fmaxf(v.z * sc.z + sh.z, 0.f);
            v.w = fmaxf(v.w * sc.w + sh.w, 0.f);
            bf16x4 b;
            b[0] = (__bf16)v.x; b[1] = (__bf16)v.y; b[2] = (__bf16)v.z; b[3] = (__bf16)v.w;
            *(bf16x4*)&sA[r * LSTR + ak] = b;
        }
        #pragma unroll
        for (int j = 0; j < 2; ++j) {
            bf16x8 v = *(const bf16x8*)&Wt[(size_t)(n0 + bn) * HD + k0 + bk + j * 8];
            *(bf16x8*)&sB[bn * LSTR + bk + j * 8] = v;
        }
        __syncthreads();

        bf16x8 af[4], bfr[4];
        #pragma unroll
        for (int i = 0; i < 4; ++i)
            af[i] = *(const bf16x8*)&sA[(mw + i * 16 + l16) * LSTR + quad * 8];
        #pragma unroll
        for (int i = 0; i < 4; ++i)
            bfr[i] = *(const bf16x8*)&sB[(nw + i * 16 + l16) * LSTR + quad * 8];
        #pragma unroll
        for (int mi = 0; mi < 4; ++mi)
            #pragma unroll
            for (int ni = 0; ni < 4; ++ni)
                acc[mi][ni] = __builtin_amdgcn_mfma_f32_16x16x32_bf16(
                    af[mi], bfr[ni], acc[mi][ni], 0, 0, 0);
        __syncthreads();
    }

    #pragma unroll
    for (int mi = 0; mi < 4; ++mi) {
        #pragma unroll
        for (int r = 0; r < 4; ++r) {
            int row = m0 + mw + mi * 16 + quad * 4 + r;
            if (row < M) {
                #pragma unroll
                for (int ni = 0; ni < 4; ++ni)
                    C[(size_t)row * HD + n0 + nw + ni * 16 + l16] = acc[mi][ni][r];
            }
        }
    }
}

// ---- CSR gather-aggregate: one 64-lane wave per dst node --------------------
__global__ void __launch_bounds__(256) gcn_aggregate(const float* __restrict__ hw,
                                                     const float* __restrict__ selfn,
                                                     const float* __restrict__ bias,
                                                     const unsigned* __restrict__ row_start,
                                                     const int* __restrict__ ecol,
                                                     const float* __restrict__ enorm,
                                                     float* __restrict__ agg) {
    int tid = blockIdx.x * 256 + threadIdx.x;
    int n = tid >> 6;            // one wave (64 lanes) per node -> uniform edge loop
    if (n >= NN) return;
    int c4 = (tid & 63) * 4;
    float s = selfn[n];
    float4 v = *(const float4*)&hw[(size_t)n * HD + c4];
    float4 acc;
    acc.x = v.x * s + bias[c4 + 0];
    acc.y = v.y * s + bias[c4 + 1];
    acc.z = v.z * s + bias[c4 + 2];
    acc.w = v.w * s + bias[c4 + 3];
    unsigned e0 = row_start[n], e1 = row_start[n + 1];
    for (unsigned e = e0; e < e1; ++e) {
        int sv = ecol[e];
        float nm = enorm[e];
        float4 u = *(const float4*)&hw[(size_t)sv * HD + c4];
        acc.x += u.x * nm;
        acc.y += u.y * nm;
        acc.z += u.z * nm;
        acc.w += u.w * nm;
    }
    *(float4*)&agg[(size_t)n * HD + c4] = acc;
}

// ---- batchnorm stats --------------------------------------------------------
__global__ void bn_stats(const float* __restrict__ h, float* __restrict__ sums) {
    int c = threadIdx.x;
    float s = 0.f, ss = 0.f;
    for (int r = blockIdx.x; r < NN; r += gridDim.x) {
        float v = h[(size_t)r * HD + c];
        s += v; ss += v * v;
    }
    unsafeAtomicAdd(&sums[c], s);
    unsafeAtomicAdd(&sums[HD + c], ss);
}

__global__ void bn_finalize(const float* __restrict__ sums,
                            const float* __restrict__ gamma,
                            const float* __restrict__ beta,
                            float* __restrict__ scale, float* __restrict__ shift) {
    int c = threadIdx.x;
    const float inv_n = 1.0f / (float)NN;
    float mu  = sums[c] * inv_n;
    float var = sums[HD + c] * inv_n - mu * mu;
    float rstd = rsqrtf(var + 1e-5f);
    float sc = gamma[c] * rstd;
    scale[c] = sc;
    shift[c] = beta[c] - mu * sc;
}

// ---- pooling + linear -------------------------------------------------------
__global__ void __launch_bounds__(256) pool_dot(const float* __restrict__ h,
                                                const float* __restrict__ lw,
                                                const int* __restrict__ batch,
                                                float* __restrict__ gsum, float* __restrict__ gcnt) {
    int tid = blockIdx.x * 256 + threadIdx.x;
    int n = tid >> 6;
    if (n >= NN) return;
    int l = tid & 63;
    int c4 = l * 4;
    float4 v = *(const float4*)&h[(size_t)n * HD + c4];
    float s = v.x * lw[c4] + v.y * lw[c4 + 1] + v.z * lw[c4 + 2] + v.w * lw[c4 + 3];
#pragma unroll
    for (int off = 32; off > 0; off >>= 1) s += __shfl_down(s, off, 64);
    if (l == 0) {
        int g = batch[n];
        unsafeAtomicAdd(&gsum[g], s);
        unsafeAtomicAdd(&gcnt[g], 1.0f);
    }
}

__global__ void final_out(const float* __restrict__ gsum, const float* __restrict__ gcnt,
                          const float* __restrict__ lb, float* __restrict__ out) {
    int g = blockIdx.x * blockDim.x + threadIdx.x;
    if (g < NG) {
        float p = gsum[g] / fmaxf(gcnt[g], 1.0f);
        out[g] = p + lb[0];
    }
}

// ---- driver -----------------------------------------------------------------
extern "C" void kernel_launch(void* const* d_in, const int* in_sizes, int n_in,
                              void* d_out, int out_size, void* d_ws, size_t ws_size,
                              hipStream_t stream) {
    const int*   x     = (const int*)d_in[0];
    const int*   ei    = (const int*)d_in[1];
    const int*   batch = (const int*)d_in[2];
    const float* emb   = (const float*)d_in[3];
    const float* Ws    = (const float*)d_in[4];
    const float* bs    = (const float*)d_in[5];
    const float* gam   = (const float*)d_in[6];
    const float* bet   = (const float*)d_in[7];
    const float* lw    = (const float*)d_in[8];
    const float* lb    = (const float*)d_in[9];
    float* out = (float*)d_out;

    const int* src = ei;
    const int* dst = ei + NE;

    // workspace carve-up (256-B aligned)
    char* p = (char*)d_ws;
    size_t off = 0;
    auto carve = [&](size_t bytes) { void* r = p + off; off = (off + bytes + 255) & ~(size_t)255; return r; };
    float*    buf0   = (float*)carve((size_t)NN * HD * 4);
    float*    buf1   = (float*)carve((size_t)NN * HD * 4);
    float*    base   = (float*)carve(HD * 4);
    float*    delta  = (float*)carve(NF * HD * 4);
    float*    dW0    = (float*)carve(NF * HD * 4);
    float*    bW0    = (float*)carve(HD * 4);
    __bf16*   dW0t   = (__bf16*)carve(HD * 64 * 2);
    __bf16*   Wt     = (__bf16*)carve((size_t)2 * HD * HD * 2);
    unsigned* deg    = (unsigned*)carve(NN * 4);
    float*    dinv   = (float*)carve(NN * 4);
    float*    selfn  = (float*)carve(NN * 4);
    float*    norm   = (float*)carve(NE * 4);
    unsigned* csum   = (unsigned*)carve(256 * 4);
    unsigned* row_s  = (unsigned*)carve((NN + 1) * 4);
    unsigned* cursor = (unsigned*)carve(NN * 4);
    int*      ecol   = (int*)carve(NE * 4);
    float*    enorm  = (float*)carve(NE * 4);
    float*    bnsum  = (float*)carve(2 * HD * 4);
    float*    scale  = (float*)carve(HD * 4);
    float*    shift  = (float*)carve(HD * 4);
    float*    gsum   = (float*)carve(NG * 4);
    float*    gcnt   = (float*)carve(NG * 4);
    (void)ws_size; (void)n_in; (void)in_sizes; (void)out_size;

    // params
    prep_emb<<<NF + 1, HD, 0, stream>>>(emb, base, delta);
    prep_w0<<<NF + 1, HD, 0, stream>>>(delta, base, Ws, dW0, bW0);
    prep_w0t<<<HD, 64, 0, stream>>>(dW0, dW0t);
    cvt_w<<<dim3(HD, 2), HD, 0, stream>>>(Ws, Wt);

    // degrees & norms
    hipMemsetAsync(deg, 0, NN * 4, stream);
    deg_kernel<<<(NE + 255) / 256, 256, 0, stream>>>(dst, deg, NE);
    dinv_kernel<<<(NN + 255) / 256, 256, 0, stream>>>(deg, dinv, selfn);
    norm_kernel<<<(NE + 255) / 256, 256, 0, stream>>>(src, dst, dinv, norm, NE);

    // CSR build (dst-sorted edge lists)
    chunk_sum<<<NCH, SCAN_CH, 0, stream>>>(deg, csum);
    chunk_scan<<<1, 256, 0, stream>>>(csum, NCH);
    chunk_apply<<<NCH, SCAN_CH, 0, stream>>>(deg, csum, row_s, cursor);
    csr_fill<<<(NE + 255) / 256, 256, 0, stream>>>(src, dst, norm, cursor, ecol, enorm, NE);

    // layer 0: MFMA encoder (X @ dW0 + bW0) -> buf1, then aggregate -> buf0
    encoder_mfma<<<dim3((NN + 127) / 128, 2), 256, 0, stream>>>(x, dW0t, bW0, buf1);
    gcn_aggregate<<<(NN * 64 + 255) / 256, 256, 0, stream>>>(
        buf1, selfn, bs, row_s, ecol, enorm, buf0);
    hipMemsetAsync(bnsum, 0, 2 * HD * 4, stream);
    bn_stats<<<512, 256, 0, stream>>>(buf0, bnsum);
    bn_finalize<<<1, HD, 0, stream>>>(bnsum, gam, bet, scale, shift);

    // layers 1,2: MFMA GEMM with fused BN-apply+relu on A
    for (int i = 1; i < 3; ++i) {
        gemm_mfma<<<dim3((NN + 127) / 128, 2), 256, 0, stream>>>(
            buf0, Wt + (size_t)(i - 1) * HD * HD, buf1, NN, scale, shift);
        gcn_aggregate<<<(NN * 64 + 255) / 256, 256, 0, stream>>>(
            buf1, selfn, bs + i * HD, row_s, ecol, enorm, buf0);
        if (i < 2) {
            hipMemsetAsync(bnsum, 0, 2 * HD * 4, stream);
            bn_stats<<<512, 256, 0, stream>>>(buf0, bnsum);
            bn_finalize<<<1, HD, 0, stream>>>(bnsum, gam + i * HD, bet + i * HD, scale, shift);
        }
    }

    // pool + linear
    hipMemsetAsync(gsum, 0, NG * 4, stream);
    hipMemsetAsync(gcnt, 0, NG * 4, stream);
    pool_dot<<<(NN * 64 + 255) / 256, 256, 0, stream>>>(buf0, lw, batch, gsum, gcnt);
    final_out<<<(NG + 255) / 256, 256, 0, stream>>>(gsum, gcnt, lb, out);
}

// Round 8
// 566.414 us; speedup vs baseline: 6.3218x; 1.1745x over previous
//
#include <hip/hip_runtime.h>
#include <hip/hip_bf16.h>

#define NN 100000      // nodes
#define NE 200000      // edges
#define NF 56          // atom feats
#define HD 256         // hidden
#define NG 2048        // graphs

#define SCAN_CH 512
#define NCH ((NN + SCAN_CH - 1) / SCAN_CH)   // 196 chunks

typedef __bf16 bf16x8 __attribute__((ext_vector_type(8)));
typedef __bf16 bf16x4 __attribute__((ext_vector_type(4)));
typedef float  floatx4 __attribute__((ext_vector_type(4)));

// ---- param prep -------------------------------------------------------------
__global__ void prep_emb(const float* __restrict__ emb,
                         float* __restrict__ base, float* __restrict__ delta) {
    int c = threadIdx.x;
    int f = blockIdx.x;
    if (f < NF) {
        float e0 = emb[(f * 2 + 0) * HD + c];
        float e1 = emb[(f * 2 + 1) * HD + c];
        delta[f * HD + c] = e1 - e0;
    } else {
        float s = 0.f;
        for (int ff = 0; ff < NF; ++ff) s += emb[(ff * 2) * HD + c];
        base[c] = s;
    }
}

// dW0[f][c] = sum_k delta[f][k] W0[k][c];  bW0[c] = sum_k base[k] W0[k][c]
__global__ void prep_w0(const float* __restrict__ delta, const float* __restrict__ base,
                        const float* __restrict__ W0,
                        float* __restrict__ dW0, float* __restrict__ bW0) {
    __shared__ float row[HD];
    int c = threadIdx.x;
    int f = blockIdx.x;
    const float* r = (f < NF) ? &delta[f * HD] : base;
    row[c] = r[c];
    __syncthreads();
    float acc = 0.f;
    for (int k = 0; k < HD; ++k) acc += row[k] * W0[k * HD + c];
    if (f < NF) dW0[f * HD + c] = acc; else bW0[c] = acc;
}

// dW0t[n][k] = bf16(dW0[k][n]), zero-padded K 56->64
__global__ void prep_w0t(const float* __restrict__ dW0, __bf16* __restrict__ dW0t) {
    int n = blockIdx.x;       // 256
    int k = threadIdx.x;      // 64
    dW0t[n * 64 + k] = (k < NF) ? (__bf16)dW0[k * HD + n] : (__bf16)0.f;
}

// Wt[l][n][k] = bf16(Ws[l+1][k][n])  -- transposed bf16 weights for layers 1,2
__global__ void cvt_w(const float* __restrict__ Ws, __bf16* __restrict__ Wt) {
    int n = blockIdx.x, l = blockIdx.y, k = threadIdx.x;
    Wt[((size_t)l * HD + n) * HD + k] = (__bf16)Ws[(size_t)(l + 1) * HD * HD + (size_t)k * HD + n];
}

// ---- degree / norm ----------------------------------------------------------
__global__ void deg_kernel(const int* __restrict__ dst, unsigned* __restrict__ deg, int E) {
    int e = blockIdx.x * blockDim.x + threadIdx.x;
    if (e < E) atomicAdd(&deg[dst[e]], 1u);
}

__global__ void dinv_kernel(const unsigned* __restrict__ deg, float* __restrict__ dinv,
                            float* __restrict__ selfn) {
    int v = blockIdx.x * blockDim.x + threadIdx.x;
    if (v < NN) {
        float d = (float)(deg[v] + 1u);   // +1 self loop
        dinv[v]  = rsqrtf(d);
        selfn[v] = 1.0f / d;              // dinv^2
    }
}

__global__ void norm_kernel(const int* __restrict__ src, const int* __restrict__ dst,
                            const float* __restrict__ dinv, float* __restrict__ norm, int E) {
    int e = blockIdx.x * blockDim.x + threadIdx.x;
    if (e < E) norm[e] = dinv[src[e]] * dinv[dst[e]];
}

// ---- CSR build: hierarchical exclusive scan of deg + counting-sort fill -----
__global__ void chunk_sum(const unsigned* __restrict__ deg, unsigned* __restrict__ csum) {
    __shared__ unsigned s[SCAN_CH];
    int t = threadIdx.x;
    int base = blockIdx.x * SCAN_CH;
    s[t] = (base + t < NN) ? deg[base + t] : 0u;
    __syncthreads();
    for (int off = SCAN_CH / 2; off > 0; off >>= 1) {
        if (t < off) s[t] += s[t + off];
        __syncthreads();
    }
    if (t == 0) csum[blockIdx.x] = s[0];
}

__global__ void chunk_scan(unsigned* __restrict__ csum, int n) {  // 1 block, 256 thr
    __shared__ unsigned s[256];
    int t = threadIdx.x;
    unsigned v = (t < n) ? csum[t] : 0u;
    s[t] = v;
    __syncthreads();
    for (int off = 1; off < 256; off <<= 1) {
        unsigned add = (t >= off) ? s[t - off] : 0u;
        __syncthreads();
        s[t] += add;
        __syncthreads();
    }
    if (t < n) csum[t] = s[t] - v;   // exclusive
}

__global__ void chunk_apply(const unsigned* __restrict__ deg, const unsigned* __restrict__ csum,
                            unsigned* __restrict__ row_start, unsigned* __restrict__ cursor) {
    __shared__ unsigned s[SCAN_CH];
    int t = threadIdx.x;
    int base = blockIdx.x * SCAN_CH;
    unsigned v = (base + t < NN) ? deg[base + t] : 0u;
    s[t] = v;
    __syncthreads();
    for (int off = 1; off < SCAN_CH; off <<= 1) {
        unsigned add = (t >= off) ? s[t - off] : 0u;
        __syncthreads();
        s[t] += add;
        __syncthreads();
    }
    if (base + t < NN) {
        unsigned rs = csum[blockIdx.x] + s[t] - v;   // exclusive scan value
        row_start[base + t] = rs;
        cursor[base + t] = rs;
    }
    if (blockIdx.x == 0 && t == 0) row_start[NN] = NE;
}

__global__ void csr_fill(const int* __restrict__ src, const int* __restrict__ dst,
                         const float* __restrict__ norm, unsigned* __restrict__ cursor,
                         int* __restrict__ ecol, float* __restrict__ enorm, int E) {
    int e = blockIdx.x * blockDim.x + threadIdx.x;
    if (e < E) {
        unsigned pos = atomicAdd(&cursor[dst[e]], 1u);
        ecol[pos] = src[e];
        enorm[pos] = norm[e];
    }
}

// ---- graph boundaries: gstart[g] = lower_bound(batch, g), batch sorted ------
__global__ void graph_bounds(const int* __restrict__ batch, unsigned* __restrict__ gstart) {
    int g = blockIdx.x * blockDim.x + threadIdx.x;
    if (g <= NG) {
        int lo = 0, hi = NN;
        while (lo < hi) {
            int mid = (lo + hi) >> 1;
            if (batch[mid] < g) lo = mid + 1; else hi = mid;
        }
        gstart[g] = (unsigned)lo;
    }
}

// ---- MFMA encoder: hw0 = X @ dW0t^T + bW0, X binary [NN,56] pad K->64 -------
#define ELSTR 72   // LDS row stride (64 + 8 pad) in bf16
__global__ void __launch_bounds__(256) encoder_mfma(const int* __restrict__ x,
                                                    const __bf16* __restrict__ dW0t,
                                                    const float* __restrict__ bW0,
                                                    float* __restrict__ C) {
    __shared__ __bf16 sA[128 * ELSTR];   // 18432 B
    __shared__ __bf16 sB[128 * ELSTR];   // 18432 B
    int t = threadIdx.x;
    int m0 = blockIdx.x * 128;
    int n0 = blockIdx.y * 128;
    int lane = t & 63, w = t >> 6;
    int quad = lane >> 4, l16 = lane & 15;
    int mw = (w & 1) * 64, nw = (w >> 1) * 64;

    {
        int r = t >> 1;
        int kh = (t & 1) * 32;
        int row = m0 + r;
        int nreal = (kh == 0) ? 32 : 24;
        #pragma unroll
        for (int j = 0; j < 8; ++j) {
            bf16x4 b;
            if (row < NN && j * 4 < nreal) {
                int4 iv = *(const int4*)&x[(size_t)row * NF + kh + j * 4];
                b[0] = (__bf16)(float)iv.x;
                b[1] = (__bf16)(float)iv.y;
                b[2] = (__bf16)(float)iv.z;
                b[3] = (__bf16)(float)iv.w;
            } else {
                b[0] = b[1] = b[2] = b[3] = (__bf16)0.f;
            }
            *(bf16x4*)&sA[r * ELSTR + kh + j * 4] = b;
        }
    }
    {
        int bn = t >> 1;
        int kh = (t & 1) * 32;
        #pragma unroll
        for (int j = 0; j < 4; ++j) {
            bf16x8 v = *(const bf16x8*)&dW0t[(size_t)(n0 + bn) * 64 + kh + j * 8];
            *(bf16x8*)&sB[bn * ELSTR + kh + j * 8] = v;
        }
    }
    __syncthreads();

    floatx4 acc[4][4] = {};
    #pragma unroll
    for (int s = 0; s < 2; ++s) {
        bf16x8 af[4], bfr[4];
        #pragma unroll
        for (int i = 0; i < 4; ++i)
            af[i] = *(const bf16x8*)&sA[(mw + i * 16 + l16) * ELSTR + s * 32 + quad * 8];
        #pragma unroll
        for (int i = 0; i < 4; ++i)
            bfr[i] = *(const bf16x8*)&sB[(nw + i * 16 + l16) * ELSTR + s * 32 + quad * 8];
        #pragma unroll
        for (int mi = 0; mi < 4; ++mi)
            #pragma unroll
            for (int ni = 0; ni < 4; ++ni)
                acc[mi][ni] = __builtin_amdgcn_mfma_f32_16x16x32_bf16(
                    af[mi], bfr[ni], acc[mi][ni], 0, 0, 0);
    }

    float bw[4];
    #pragma unroll
    for (int ni = 0; ni < 4; ++ni) bw[ni] = bW0[n0 + nw + ni * 16 + l16];
    #pragma unroll
    for (int mi = 0; mi < 4; ++mi) {
        #pragma unroll
        for (int r = 0; r < 4; ++r) {
            int row = m0 + mw + mi * 16 + quad * 4 + r;
            if (row < NN) {
                #pragma unroll
                for (int ni = 0; ni < 4; ++ni)
                    C[(size_t)row * HD + n0 + nw + ni * 16 + l16] = acc[mi][ni][r] + bw[ni];
            }
        }
    }
}

// ---- bf16 MFMA GEMM: C[M,256] = relu_bn(A) @ W, 128x128 tile ----------------
#define LSTR 40   // LDS row stride in bf16 (32 data + 8 pad)
__global__ void __launch_bounds__(256) gemm_mfma(const float* __restrict__ A,
                                                 const __bf16* __restrict__ Wt,
                                                 float* __restrict__ C, int M,
                                                 const float* __restrict__ ascale,
                                                 const float* __restrict__ ashift) {
    __shared__ __bf16 sA[128 * LSTR];   // 10240 B
    __shared__ __bf16 sB[128 * LSTR];   // 10240 B
    int t = threadIdx.x;
    int m0 = blockIdx.x * 128;
    int n0 = blockIdx.y * 128;
    int lane = t & 63, w = t >> 6;
    int quad = lane >> 4, l16 = lane & 15;
    int mw = (w & 1) * 64, nw = (w >> 1) * 64;

    int ar = t >> 3;
    int ak = (t & 7) * 4;
    int bn = t >> 1;
    int bk = (t & 1) * 16;

    floatx4 acc[4][4] = {};

    for (int k0 = 0; k0 < 256; k0 += 32) {
        float4 sc = *(const float4*)&ascale[k0 + ak];
        float4 sh = *(const float4*)&ashift[k0 + ak];
        #pragma unroll
        for (int p = 0; p < 4; ++p) {
            int r = p * 32 + ar;
            int row = m0 + r;
            float4 v = make_float4(0.f, 0.f, 0.f, 0.f);
            if (row < M) v = *(const float4*)&A[(size_t)row * HD + k0 + ak];
            v.x = fmaxf(v.x * sc.x + sh.x, 0.f);
            v.y = fmaxf(v.y * sc.y + sh.y, 0.f);
            v.z = fmaxf(v.z * sc.z + sh.z, 0.f);
            v.w = fmaxf(v.w * sc.w + sh.w, 0.f);
            bf16x4 b;
            b[0] = (__bf16)v.x; b[1] = (__bf16)v.y; b[2] = (__bf16)v.z; b[3] = (__bf16)v.w;
            *(bf16x4*)&sA[r * LSTR + ak] = b;
        }
        #pragma unroll
        for (int j = 0; j < 2; ++j) {
            bf16x8 v = *(const bf16x8*)&Wt[(size_t)(n0 + bn) * HD + k0 + bk + j * 8];
            *(bf16x8*)&sB[bn * LSTR + bk + j * 8] = v;
        }
        __syncthreads();

        bf16x8 af[4], bfr[4];
        #pragma unroll
        for (int i = 0; i < 4; ++i)
            af[i] = *(const bf16x8*)&sA[(mw + i * 16 + l16) * LSTR + quad * 8];
        #pragma unroll
        for (int i = 0; i < 4; ++i)
            bfr[i] = *(const bf16x8*)&sB[(nw + i * 16 + l16) * LSTR + quad * 8];
        #pragma unroll
        for (int mi = 0; mi < 4; ++mi)
            #pragma unroll
            for (int ni = 0; ni < 4; ++ni)
                acc[mi][ni] = __builtin_amdgcn_mfma_f32_16x16x32_bf16(
                    af[mi], bfr[ni], acc[mi][ni], 0, 0, 0);
        __syncthreads();
    }

    #pragma unroll
    for (int mi = 0; mi < 4; ++mi) {
        #pragma unroll
        for (int r = 0; r < 4; ++r) {
            int row = m0 + mw + mi * 16 + quad * 4 + r;
            if (row < M) {
                #pragma unroll
                for (int ni = 0; ni < 4; ++ni)
                    C[(size_t)row * HD + n0 + nw + ni * 16 + l16] = acc[mi][ni][r];
            }
        }
    }
}

// ---- CSR gather-aggregate; optional fused lin_w dot (final layer) -----------
// agg[n] = hw[n]*selfn[n] + bias + sum_{e} enorm[e]*hw[ecol[e]]
// If dotout != nullptr: write dot[n] = agg_row . lw instead of the agg row.
__global__ void __launch_bounds__(256) gcn_aggregate(const float* __restrict__ hw,
                                                     const float* __restrict__ selfn,
                                                     const float* __restrict__ bias,
                                                     const unsigned* __restrict__ row_start,
                                                     const int* __restrict__ ecol,
                                                     const float* __restrict__ enorm,
                                                     float* __restrict__ agg,
                                                     const float* __restrict__ lw,
                                                     float* __restrict__ dotout) {
    int tid = blockIdx.x * 256 + threadIdx.x;
    int n = tid >> 6;            // one wave (64 lanes) per node
    if (n >= NN) return;
    int c4 = (tid & 63) * 4;
    float s = selfn[n];
    float4 v = *(const float4*)&hw[(size_t)n * HD + c4];
    float4 acc;
    acc.x = v.x * s + bias[c4 + 0];
    acc.y = v.y * s + bias[c4 + 1];
    acc.z = v.z * s + bias[c4 + 2];
    acc.w = v.w * s + bias[c4 + 3];
    unsigned e0 = row_start[n], e1 = row_start[n + 1];
    for (unsigned e = e0; e < e1; ++e) {
        int sv = ecol[e];
        float nm = enorm[e];
        float4 u = *(const float4*)&hw[(size_t)sv * HD + c4];
        acc.x += u.x * nm;
        acc.y += u.y * nm;
        acc.z += u.z * nm;
        acc.w += u.w * nm;
    }
    if (dotout) {
        float d = acc.x * lw[c4] + acc.y * lw[c4 + 1] + acc.z * lw[c4 + 2] + acc.w * lw[c4 + 3];
        #pragma unroll
        for (int off = 32; off > 0; off >>= 1) d += __shfl_down(d, off, 64);
        if ((tid & 63) == 0) dotout[n] = d;
    } else {
        *(float4*)&agg[(size_t)n * HD + c4] = acc;
    }
}

// ---- batchnorm stats --------------------------------------------------------
__global__ void bn_stats(const float* __restrict__ h, float* __restrict__ sums) {
    int c = threadIdx.x;
    float s = 0.f, ss = 0.f;
    for (int r = blockIdx.x; r < NN; r += gridDim.x) {
        float v = h[(size_t)r * HD + c];
        s += v; ss += v * v;
    }
    unsafeAtomicAdd(&sums[c], s);
    unsafeAtomicAdd(&sums[HD + c], ss);
}

__global__ void bn_finalize(const float* __restrict__ sums,
                            const float* __restrict__ gamma,
                            const float* __restrict__ beta,
                            float* __restrict__ scale, float* __restrict__ shift) {
    int c = threadIdx.x;
    const float inv_n = 1.0f / (float)NN;
    float mu  = sums[c] * inv_n;
    float var = sums[HD + c] * inv_n - mu * mu;
    float rstd = rsqrtf(var + 1e-5f);
    float sc = gamma[c] * rstd;
    scale[c] = sc;
    shift[c] = beta[c] - mu * sc;
}

// ---- pooling: one wave per graph over contiguous dot[] segment --------------
__global__ void __launch_bounds__(256) pool_graphs(const float* __restrict__ dot,
                                                   const unsigned* __restrict__ gstart,
                                                   const float* __restrict__ lb,
                                                   float* __restrict__ out) {
    int tid = blockIdx.x * 256 + threadIdx.x;
    int g = tid >> 6;
    if (g >= NG) return;
    int l = tid & 63;
    unsigned s0 = gstart[g], s1 = gstart[g + 1];
    float s = 0.f;
    for (unsigned i = s0 + l; i < s1; i += 64) s += dot[i];
    #pragma unroll
    for (int off = 32; off > 0; off >>= 1) s += __shfl_down(s, off, 64);
    if (l == 0) out[g] = s / fmaxf((float)(s1 - s0), 1.0f) + lb[0];
}

// ---- driver -----------------------------------------------------------------
extern "C" void kernel_launch(void* const* d_in, const int* in_sizes, int n_in,
                              void* d_out, int out_size, void* d_ws, size_t ws_size,
                              hipStream_t stream) {
    const int*   x     = (const int*)d_in[0];
    const int*   ei    = (const int*)d_in[1];
    const int*   batch = (const int*)d_in[2];
    const float* emb   = (const float*)d_in[3];
    const float* Ws    = (const float*)d_in[4];
    const float* bs    = (const float*)d_in[5];
    const float* gam   = (const float*)d_in[6];
    const float* bet   = (const float*)d_in[7];
    const float* lw    = (const float*)d_in[8];
    const float* lb    = (const float*)d_in[9];
    float* out = (float*)d_out;

    const int* src = ei;
    const int* dst = ei + NE;

    // workspace carve-up (256-B aligned)
    char* p = (char*)d_ws;
    size_t off = 0;
    auto carve = [&](size_t bytes) { void* r = p + off; off = (off + bytes + 255) & ~(size_t)255; return r; };
    float*    buf0   = (float*)carve((size_t)NN * HD * 4);
    float*    buf1   = (float*)carve((size_t)NN * HD * 4);
    float*    base   = (float*)carve(HD * 4);
    float*    delta  = (float*)carve(NF * HD * 4);
    float*    dW0    = (float*)carve(NF * HD * 4);
    float*    bW0    = (float*)carve(HD * 4);
    __bf16*   dW0t   = (__bf16*)carve(HD * 64 * 2);
    __bf16*   Wt     = (__bf16*)carve((size_t)2 * HD * HD * 2);
    unsigned* deg    = (unsigned*)carve(NN * 4);
    float*    dinv   = (float*)carve(NN * 4);
    float*    selfn  = (float*)carve(NN * 4);
    float*    norm   = (float*)carve(NE * 4);
    unsigned* csum   = (unsigned*)carve(256 * 4);
    unsigned* row_s  = (unsigned*)carve((NN + 1) * 4);
    unsigned* cursor = (unsigned*)carve(NN * 4);
    int*      ecol   = (int*)carve(NE * 4);
    float*    enorm  = (float*)carve(NE * 4);
    float*    bnsum  = (float*)carve(2 * HD * 4);
    float*    scale  = (float*)carve(HD * 4);
    float*    shift  = (float*)carve(HD * 4);
    unsigned* gstart = (unsigned*)carve((NG + 1) * 4);
    float*    dotbuf = (float*)carve(NN * 4);
    (void)ws_size; (void)n_in; (void)in_sizes; (void)out_size;

    // params
    prep_emb<<<NF + 1, HD, 0, stream>>>(emb, base, delta);
    prep_w0<<<NF + 1, HD, 0, stream>>>(delta, base, Ws, dW0, bW0);
    prep_w0t<<<HD, 64, 0, stream>>>(dW0, dW0t);
    cvt_w<<<dim3(HD, 2), HD, 0, stream>>>(Ws, Wt);

    // degrees & norms
    hipMemsetAsync(deg, 0, NN * 4, stream);
    deg_kernel<<<(NE + 255) / 256, 256, 0, stream>>>(dst, deg, NE);
    dinv_kernel<<<(NN + 255) / 256, 256, 0, stream>>>(deg, dinv, selfn);
    norm_kernel<<<(NE + 255) / 256, 256, 0, stream>>>(src, dst, dinv, norm, NE);

    // CSR build (dst-sorted edge lists) + graph bounds
    chunk_sum<<<NCH, SCAN_CH, 0, stream>>>(deg, csum);
    chunk_scan<<<1, 256, 0, stream>>>(csum, NCH);
    chunk_apply<<<NCH, SCAN_CH, 0, stream>>>(deg, csum, row_s, cursor);
    csr_fill<<<(NE + 255) / 256, 256, 0, stream>>>(src, dst, norm, cursor, ecol, enorm, NE);
    graph_bounds<<<(NG + 256) / 256, 256, 0, stream>>>(batch, gstart);

    // layer 0: MFMA encoder -> buf1, aggregate -> buf0
    encoder_mfma<<<dim3((NN + 127) / 128, 2), 256, 0, stream>>>(x, dW0t, bW0, buf1);
    gcn_aggregate<<<(NN * 64 + 255) / 256, 256, 0, stream>>>(
        buf1, selfn, bs, row_s, ecol, enorm, buf0, nullptr, nullptr);
    hipMemsetAsync(bnsum, 0, 2 * HD * 4, stream);
    bn_stats<<<512, 256, 0, stream>>>(buf0, bnsum);
    bn_finalize<<<1, HD, 0, stream>>>(bnsum, gam, bet, scale, shift);

    // layer 1: MFMA GEMM (fused BN+relu on A) -> buf1, aggregate -> buf0
    gemm_mfma<<<dim3((NN + 127) / 128, 2), 256, 0, stream>>>(
        buf0, Wt, buf1, NN, scale, shift);
    gcn_aggregate<<<(NN * 64 + 255) / 256, 256, 0, stream>>>(
        buf1, selfn, bs + HD, row_s, ecol, enorm, buf0, nullptr, nullptr);
    hipMemsetAsync(bnsum, 0, 2 * HD * 4, stream);
    bn_stats<<<512, 256, 0, stream>>>(buf0, bnsum);
    bn_finalize<<<1, HD, 0, stream>>>(bnsum, gam + HD, bet + HD, scale, shift);

    // layer 2: GEMM -> buf1, aggregate fused with lin_w dot -> dotbuf
    gemm_mfma<<<dim3((NN + 127) / 128, 2), 256, 0, stream>>>(
        buf0, Wt + (size_t)HD * HD, buf1, NN, scale, shift);
    gcn_aggregate<<<(NN * 64 + 255) / 256, 256, 0, stream>>>(
        buf1, selfn, bs + 2 * HD, row_s, ecol, enorm, nullptr, lw, dotbuf);

    // pool: one wave per graph, atomic-free
    pool_graphs<<<(NG * 64 + 255) / 256, 256, 0, stream>>>(dotbuf, gstart, lb, out);
}